// Round 13
// baseline (348.992 us; speedup 1.0000x reference)
//
#include <hip/hip_runtime.h>
#include <math.h>

#define NB   8
#define CIN  512
#define COUT 256
#define DIN  512
#define LHW  4096
#define NCHK 128
#define CHL  32
#define PW   66
#define PPOS (PW*PW)

typedef __attribute__((ext_vector_type(8))) short bf16x8;
typedef __attribute__((ext_vector_type(4))) float f32x4;

__device__ __forceinline__ float siluf(float v)  { return v / (1.f + __expf(-v)); }
__device__ __forceinline__ float splusf(float v) {
  return fmaxf(v, 0.f) + __logf(1.f + __expf(-fabsf(v)));
}

__device__ __forceinline__ unsigned short f2b(float f) {
  union { float f; unsigned u; } v; v.f = f;
  unsigned r = v.u + 0x7fff + ((v.u >> 16) & 1);
  return (unsigned short)(r >> 16);
}
__device__ __forceinline__ float b2f(unsigned int u) {
  union { unsigned u; float f; } v; v.u = (u & 0xffffu) << 16; return v.f;
}

__device__ __forceinline__ void gload16(const unsigned short* g, unsigned short* l) {
  __builtin_amdgcn_global_load_lds(
      (const __attribute__((address_space(1))) unsigned int*)g,
      (__attribute__((address_space(3))) unsigned int*)l, 16, 0, 0);
}

// ---------------------------------------------------------------------------
// W: weight prep — convert GEMM weights to bf16 + build fused dt/proj B-matrix
// ---------------------------------------------------------------------------
#define WO1 131072
#define WO2 393216
#define WO3 425984
#define WO4 557056
#define WO5 1146880
__global__ __launch_bounds__(256)
void k_wprep(const float* __restrict__ lw, const float* __restrict__ ipw,
             const float* __restrict__ xpw, const float* __restrict__ opw,
             const float* __restrict__ rw, const float* __restrict__ dtpw,
             unsigned short* __restrict__ wb, unsigned short* __restrict__ wfb) {
  const int i = blockIdx.x * 256 + threadIdx.x;
  if (i < WO1)      wb[i] = f2b(lw[i]);
  else if (i < WO2) wb[i] = f2b(ipw[i - WO1]);
  else if (i < WO3) {
    const int j = i - WO2, row = j >> 9, col = j & 511;
    wb[i] = (row < 48) ? f2b(xpw[row * 512 + col]) : (unsigned short)0;
  }
  else if (i < WO4) wb[i] = f2b(opw[i - WO3]);
  else if (i < WO5) {
    const int j = i - WO4, o = j / 2304, kk = j % 2304;
    const int tap = kk >> 8, ch = kk & 255;
    wb[i] = f2b(rw[(o * 256 + ch) * 9 + tap]);
  }
  else {
    const int j = i - WO5, row = j >> 9, e = j & 511;
    float v = 0.f;
    if (row < 512) {
#pragma unroll
      for (int r = 0; r < 16; ++r)
        v = fmaf(dtpw[row * 16 + r], xpw[r * 512 + e], v);
    } else if (row < 560) {
      v = xpw[(row - 512) * 512 + e];
    }
    wfb[j] = f2b(v);
  }
}

// ---------------------------------------------------------------------------
// T: transpose x (b,k,l) f32 -> xt (b,l,k) bf16
// ---------------------------------------------------------------------------
__global__ __launch_bounds__(256)
void k_xpose(const float* __restrict__ x, unsigned short* __restrict__ xt) {
  __shared__ unsigned short Ts[64][80];
  const int b  = blockIdx.z;
  const int k0 = blockIdx.y * 64;
  const int l0 = blockIdx.x * 64;
  const int t  = threadIdx.x;
  const int tx = t & 15, ty = t >> 4;
#pragma unroll
  for (int r = 0; r < 4; ++r) {
    const int k = ty + r * 16;
    float4 v = *(const float4*)(x + ((size_t)b * CIN + k0 + k) * LHW + l0 + tx * 4);
    Ts[tx*4+0][k] = f2b(v.x);
    Ts[tx*4+1][k] = f2b(v.y);
    Ts[tx*4+2][k] = f2b(v.z);
    Ts[tx*4+3][k] = f2b(v.w);
  }
  __syncthreads();
  const int lr = t >> 2, kc = (t & 3) * 16;
  unsigned short* dst = xt + ((size_t)b * LHW + l0 + lr) * CIN + k0 + kc;
  *(uint4*)dst       = *(const uint4*)&Ts[lr][kc];
  *(uint4*)(dst + 8) = *(const uint4*)&Ts[lr][kc + 8];
}

// ---------------------------------------------------------------------------
// shared MFMA main loop: 128x128 tile, BK=64 + XOR-swizzled LDS (R12-proven)
// ---------------------------------------------------------------------------
template<int RSA, int RSB, int KTOT>
__device__ __forceinline__ void gemm_loop_128(
    const unsigned short* __restrict__ Ab, const unsigned short* __restrict__ Bb,
    unsigned short (&As)[2][4096], unsigned short (&Bs)[2][4096],
    int t, f32x4 acc[4][4]) {
  const int w = t >> 6, lane = t & 63;
  const int wm = w >> 1, wn = w & 1;
  const int arow = t >> 2;
  const int acol = (((t & 3) ^ ((t >> 3) & 3))) * 8;
  const int fr = lane & 15;
  const int g8 = ((lane >> 4) * 8) ^ (((fr >> 1) & 3) * 8);
  for (int k0 = 0; k0 < KTOT; k0 += 64) {
    __syncthreads();
    gload16(Ab + (size_t)arow * RSA + k0 + acol,             &As[0][w * 512]);
    gload16(Ab + (size_t)(64 + arow) * RSA + k0 + acol,      &As[0][2048 + w*512]);
    gload16(Bb + (size_t)arow * RSB + k0 + acol,             &Bs[0][w * 512]);
    gload16(Bb + (size_t)(64 + arow) * RSB + k0 + acol,      &Bs[0][2048 + w*512]);
    gload16(Ab + (size_t)arow * RSA + k0 + 32 + acol,        &As[1][w * 512]);
    gload16(Ab + (size_t)(64 + arow) * RSA + k0 + 32 + acol, &As[1][2048 + w*512]);
    gload16(Bb + (size_t)arow * RSB + k0 + 32 + acol,        &Bs[1][w * 512]);
    gload16(Bb + (size_t)(64 + arow) * RSB + k0 + 32 + acol, &Bs[1][2048 + w*512]);
    __syncthreads();
#pragma unroll
    for (int h = 0; h < 2; ++h) {
      bf16x8 af[4], bf[4];
#pragma unroll
      for (int f = 0; f < 4; ++f) {
        af[f] = *(const bf16x8*)&As[h][(wm*64 + f*16 + fr) * 32 + g8];
        bf[f] = *(const bf16x8*)&Bs[h][(wn*64 + f*16 + fr) * 32 + g8];
      }
#pragma unroll
      for (int i = 0; i < 4; ++i)
#pragma unroll
        for (int j = 0; j < 4; ++j)
          acc[i][j] = __builtin_amdgcn_mfma_f32_16x16x32_bf16(af[i], bf[j], acc[i][j], 0, 0, 0);
    }
  }
}

// ---------------------------------------------------------------------------
// G1: lateral
// ---------------------------------------------------------------------------
__global__ __launch_bounds__(256)
void k_lat_mfma(const unsigned short* __restrict__ xt, const unsigned short* __restrict__ lwb,
                const float* __restrict__ lb, unsigned short* __restrict__ ub) {
  __shared__ __align__(16) unsigned short As[2][4096], Bs[2][4096];
  const int t = threadIdx.x, lane = t & 63, w = t >> 6;
  const int wm = w >> 1, wn = w & 1;
  const int b = blockIdx.z, m0 = blockIdx.y * 128, n0 = blockIdx.x * 128;
  f32x4 acc[4][4] = {};
  gemm_loop_128<512, 512, 512>(xt + ((size_t)b * LHW + m0) * 512,
                               lwb + (size_t)n0 * 512, As, Bs, t, acc);
  const int fr = lane & 15, q4 = (lane >> 4) * 4;
#pragma unroll
  for (int i = 0; i < 4; ++i) {
    const int l = m0 + wm*64 + i*16 + q4;
#pragma unroll
    for (int j = 0; j < 4; ++j) {
      const int o = n0 + wn*64 + j*16 + fr;
      const float bias = lb[o];
      unsigned short* dst = ub + ((size_t)b * LHW + l) * COUT + o;
#pragma unroll
      for (int q = 0; q < 4; ++q)
        dst[(size_t)q * COUT] = f2b(acc[i][j][q] + bias);
    }
  }
}

// ---------------------------------------------------------------------------
// G2: inproj
// ---------------------------------------------------------------------------
__global__ __launch_bounds__(256)
void k_inproj_mfma(const unsigned short* __restrict__ ub, const unsigned short* __restrict__ ipwb,
                   unsigned short* __restrict__ xm_b, unsigned short* __restrict__ zsb) {
  __shared__ __align__(16) unsigned short As[2][4096], Bs[2][4096];
  const int t = threadIdx.x, lane = t & 63, w = t >> 6;
  const int wm = w >> 1, wn = w & 1;
  const int b = blockIdx.z, m0 = blockIdx.y * 128, n0 = blockIdx.x * 128;
  f32x4 acc[4][4] = {};
  gemm_loop_128<256, 256, 256>(ub + ((size_t)b * LHW + m0) * 256,
                               ipwb + (size_t)n0 * 256, As, Bs, t, acc);
  const int fr = lane & 15, q4 = (lane >> 4) * 4;
  const bool isz = (n0 >= 512);
#pragma unroll
  for (int i = 0; i < 4; ++i) {
    const int l = m0 + wm*64 + i*16 + q4;
#pragma unroll
    for (int j = 0; j < 4; ++j) {
      const int e = n0 + wn*64 + j*16 + fr;
      if (isz) {
        unsigned short* dst = zsb + ((size_t)b * LHW + l) * DIN + (e - 512);
#pragma unroll
        for (int q = 0; q < 4; ++q)
          dst[(size_t)q * DIN] = f2b(siluf(acc[i][j][q]));
      } else {
        unsigned short* dst = xm_b + ((size_t)b * LHW + l) * DIN + e;
#pragma unroll
        for (int q = 0; q < 4; ++q)
          dst[(size_t)q * DIN] = f2b(acc[i][j][q]);
      }
    }
  }
}

// ---------------------------------------------------------------------------
// K3: depthwise causal conv1d, 8 rows/thread
// ---------------------------------------------------------------------------
__global__ __launch_bounds__(256)
void k_conv1d(const unsigned short* __restrict__ xm_b, const float* __restrict__ cw,
              const float* __restrict__ cb, unsigned short* __restrict__ xc_b) {
  const int tid = blockIdx.x * 256 + threadIdx.x;
  const int e8 = tid & 63;
  const int lg = tid >> 6;
  const int l0 = (lg & 511) * 8;
  const int b  = lg >> 9;
  const int e0 = e8 * 8;
  float bias[8];
  *(float4*)&bias[0] = *(const float4*)(cb + e0);
  *(float4*)&bias[4] = *(const float4*)(cb + e0 + 4);
  float wv[8][4];
#pragma unroll
  for (int q = 0; q < 8; ++q) {
    float4 w4 = *(const float4*)(cw + (e0 + q) * 4);
    wv[q][0] = w4.x; wv[q][1] = w4.y; wv[q][2] = w4.z; wv[q][3] = w4.w;
  }
  const unsigned short* base = xm_b + ((size_t)b * LHW + l0) * DIN + e0;
  uint4 rows[11];
  const uint4 z4 = make_uint4(0u, 0u, 0u, 0u);
#pragma unroll
  for (int r = 0; r < 11; ++r) {
    const int ll = r - 3;
    rows[r] = (l0 + ll >= 0) ? *(const uint4*)(base + (ptrdiff_t)ll * DIN) : z4;
  }
  unsigned short* outb = xc_b + ((size_t)b * LHW + l0) * DIN + e0;
#pragma unroll
  for (int j = 0; j < 8; ++j) {
    float acc[8];
#pragma unroll
    for (int q = 0; q < 8; ++q) acc[q] = bias[q];
#pragma unroll
    for (int k = 0; k < 4; ++k) {
      const uint4 raw = rows[j + k];
      acc[0] = fmaf(b2f(raw.x),       wv[0][k], acc[0]);
      acc[1] = fmaf(b2f(raw.x >> 16), wv[1][k], acc[1]);
      acc[2] = fmaf(b2f(raw.y),       wv[2][k], acc[2]);
      acc[3] = fmaf(b2f(raw.y >> 16), wv[3][k], acc[3]);
      acc[4] = fmaf(b2f(raw.z),       wv[4][k], acc[4]);
      acc[5] = fmaf(b2f(raw.z >> 16), wv[5][k], acc[5]);
      acc[6] = fmaf(b2f(raw.w),       wv[6][k], acc[6]);
      acc[7] = fmaf(b2f(raw.w >> 16), wv[7][k], acc[7]);
    }
    uint4 o;
    o.x = (unsigned)f2b(siluf(acc[0])) | ((unsigned)f2b(siluf(acc[1])) << 16);
    o.y = (unsigned)f2b(siluf(acc[2])) | ((unsigned)f2b(siluf(acc[3])) << 16);
    o.z = (unsigned)f2b(siluf(acc[4])) | ((unsigned)f2b(siluf(acc[5])) << 16);
    o.w = (unsigned)f2b(siluf(acc[6])) | ((unsigned)f2b(siluf(acc[7])) << 16);
    *(uint4*)(outb + (size_t)j * DIN) = o;
  }
}

// ---------------------------------------------------------------------------
// G3: fused xproj+dt GEMM
// ---------------------------------------------------------------------------
__global__ __launch_bounds__(256)
void k_xdt_mfma(const unsigned short* __restrict__ xc_b, const unsigned short* __restrict__ wfb,
                const float* __restrict__ dtpb,
                unsigned short* __restrict__ dtb, float* __restrict__ proj) {
  __shared__ __align__(16) unsigned short As[2][4096], Bs[2][4096];
  const int t = threadIdx.x, lane = t & 63, w = t >> 6;
  const int wm = w >> 1, wn = w & 1;
  const int b = blockIdx.z, m0 = blockIdx.x * 128, n0 = blockIdx.y * 128;
  f32x4 acc[4][4] = {};
  gemm_loop_128<512, 512, 512>(xc_b + ((size_t)b * LHW + m0) * 512,
                               wfb + (size_t)n0 * 512, As, Bs, t, acc);
  const int fr = lane & 15, q4 = (lane >> 4) * 4;
#pragma unroll
  for (int i = 0; i < 4; ++i) {
    const int l = m0 + wm*64 + i*16 + q4;
#pragma unroll
    for (int j = 0; j < 4; ++j) {
      const int c = n0 + wn*64 + j*16 + fr;
      if (c < 512) {
        const float bias = dtpb[c];
        unsigned short* dst = dtb + ((size_t)b * LHW + l) * 512 + c;
#pragma unroll
        for (int q = 0; q < 4; ++q)
          dst[(size_t)q * 512] = f2b(splusf(acc[i][j][q] + bias));
      } else if (c < 560) {
        float* dst = proj + ((size_t)b * LHW + l) * 48 + (c - 512);
#pragma unroll
        for (int q = 0; q < 4; ++q)
          dst[(size_t)q * 48] = acc[i][j][q];
      }
    }
  }
}

// ---------------------------------------------------------------------------
// K5: scan phase A — n-split: thread pair (d, half) handles 8 states each.
// Outputs: Sst (local end states, 16 f32 per chunk-d), SDT (sum of dt per chunk-d)
// ---------------------------------------------------------------------------
__global__ __launch_bounds__(512, 4)
void k_scanA(const float* __restrict__ proj, const unsigned short* __restrict__ dtb,
             const unsigned short* __restrict__ xc_b, const float* __restrict__ A_log,
             float* __restrict__ Sst, float* __restrict__ SDT) {
  __shared__ float prs[CHL * 16];
  const int chunkid = blockIdx.x >> 1;
  const int dg = blockIdx.x & 1;
  const int b = chunkid >> 7, c = chunkid & 127;
  const int t = threadIdx.x;
  const int d = dg * 256 + (t >> 1);
  const int hf = t & 1;
  const size_t rbase = (size_t)b * LHW + c * CHL;
  for (int i = t; i < CHL * 4; i += 512) {
    const int row = i >> 2, c4 = i & 3;
    *(float4*)&prs[row * 16 + c4 * 4] = *(const float4*)(proj + (rbase + row) * 48 + 16 + c4 * 4);
  }
  float An[8], h[8];
  {
    float4 a0 = *(const float4*)(A_log + d*16 + hf*8);
    float4 a1 = *(const float4*)(A_log + d*16 + hf*8 + 4);
    An[0]=-__expf(a0.x); An[1]=-__expf(a0.y); An[2]=-__expf(a0.z); An[3]=-__expf(a0.w);
    An[4]=-__expf(a1.x); An[5]=-__expf(a1.y); An[6]=-__expf(a1.z); An[7]=-__expf(a1.w);
  }
  const float An0g = -__expf(A_log[d * 16]);
#pragma unroll
  for (int k = 0; k < 8; ++k) h[k] = 0.f;
  bool lin = true;
#pragma unroll
  for (int k = 0; k < 8; ++k)
    lin = lin && (fabsf(An[k] - (hf*8 + k + 1) * An0g) <= 1e-4f * fabsf(An[k]));
  float sdt = 0.f;
  const unsigned short* dt0 = dtb + rbase * 512 + d;
  const unsigned short* xc0 = xc_b + rbase * DIN + d;
  __syncthreads();
  for (int i = 0; i < CHL; ++i) {
    const float dt = b2f(dt0[(size_t)i * 512]);
    sdt += dt;
    const float dtx = dt * b2f(xc0[(size_t)i * DIN]);
    float dA[8];
    if (lin) {
      const float e1 = __expf(dt * An0g);
      const float e2 = e1*e1, e3 = e2*e1, e4 = e2*e2;
      const float e8 = e4*e4;
      const float st = e1 * (hf ? e8 : 1.f);
      dA[0]=st; dA[1]=st*e1; dA[2]=st*e2; dA[3]=st*e3;
      dA[4]=dA[0]*e4; dA[5]=dA[1]*e4; dA[6]=dA[2]*e4; dA[7]=dA[3]*e4;
    } else {
#pragma unroll
      for (int k = 0; k < 8; ++k) dA[k] = __expf(dt * An[k]);
    }
    const float* pr = &prs[i * 16 + hf * 8];
    float4 B0 = *(const float4*)pr;
    float4 B1 = *(const float4*)(pr + 4);
    h[0]=fmaf(dA[0],h[0],dtx*B0.x); h[1]=fmaf(dA[1],h[1],dtx*B0.y);
    h[2]=fmaf(dA[2],h[2],dtx*B0.z); h[3]=fmaf(dA[3],h[3],dtx*B0.w);
    h[4]=fmaf(dA[4],h[4],dtx*B1.x); h[5]=fmaf(dA[5],h[5],dtx*B1.y);
    h[6]=fmaf(dA[6],h[6],dtx*B1.z); h[7]=fmaf(dA[7],h[7],dtx*B1.w);
  }
  float* o = Sst + ((size_t)chunkid * 512 + d) * 16 + hf * 8;
  *(float4*)o       = make_float4(h[0], h[1], h[2], h[3]);
  *(float4*)(o + 4) = make_float4(h[4], h[5], h[6], h[7]);
  if (!hf) SDT[(size_t)chunkid * 512 + d] = sdt;
}

// ---------------------------------------------------------------------------
// K6: scan phase B — combine chunk summaries (P reconstructed from SDT)
// ---------------------------------------------------------------------------
__global__ __launch_bounds__(256)
void k_scanB(const float* __restrict__ Sst, const float* __restrict__ SDT,
             const float* __restrict__ A_log, float* __restrict__ hst) {
  const int tid = blockIdx.x * 256 + threadIdx.x;
  const int n = tid & 15;
  const int d = (tid >> 4) & 511;
  const int b = tid >> 13;
  const float An = -__expf(A_log[d * 16 + n]);
  float h = 0.f;
  for (int c = 0; c < NCHK; ++c) {
    const size_t idx = (size_t)((b*NCHK + c)*512 + d);
    hst[idx*16 + n] = h;
    h = __expf(SDT[idx] * An) * h + Sst[idx*16 + n];
  }
}

// ---------------------------------------------------------------------------
// K7: scan phase C — n-split; pair combines y via shfl_xor
// ---------------------------------------------------------------------------
__global__ __launch_bounds__(512, 4)
void k_scanC(const float* __restrict__ proj, const unsigned short* __restrict__ dtb,
             const unsigned short* __restrict__ xc_b,
             const unsigned short* __restrict__ zsb, const float* __restrict__ hst,
             const float* __restrict__ A_log, const float* __restrict__ Dpar,
             unsigned short* __restrict__ ydata) {
  __shared__ float prs[CHL * 32];
  const int chunkid = blockIdx.x >> 1;
  const int dg = blockIdx.x & 1;
  const int b = chunkid >> 7, c = chunkid & 127;
  const int t = threadIdx.x;
  const int d = dg * 256 + (t >> 1);
  const int hf = t & 1;
  const size_t rbase = (size_t)b * LHW + c * CHL;
  for (int i = t; i < CHL * 8; i += 512) {
    const int row = i >> 3, c4 = i & 7;
    *(float4*)&prs[row * 32 + c4 * 4] = *(const float4*)(proj + (rbase + row) * 48 + 16 + c4 * 4);
  }
  float An[8], h[8];
  {
    float4 a0 = *(const float4*)(A_log + d*16 + hf*8);
    float4 a1 = *(const float4*)(A_log + d*16 + hf*8 + 4);
    An[0]=-__expf(a0.x); An[1]=-__expf(a0.y); An[2]=-__expf(a0.z); An[3]=-__expf(a0.w);
    An[4]=-__expf(a1.x); An[5]=-__expf(a1.y); An[6]=-__expf(a1.z); An[7]=-__expf(a1.w);
  }
  const float An0g = -__expf(A_log[d * 16]);
  {
    const float* hsrc = hst + ((size_t)chunkid * 512 + d) * 16 + hf * 8;
    float4 h0 = *(const float4*)hsrc;
    float4 h1 = *(const float4*)(hsrc + 4);
    h[0]=h0.x; h[1]=h0.y; h[2]=h0.z; h[3]=h0.w;
    h[4]=h1.x; h[5]=h1.y; h[6]=h1.z; h[7]=h1.w;
  }
  bool lin = true;
#pragma unroll
  for (int k = 0; k < 8; ++k)
    lin = lin && (fabsf(An[k] - (hf*8 + k + 1) * An0g) <= 1e-4f * fabsf(An[k]));
  const float dp = Dpar[d];
  const unsigned short* dt0 = dtb + rbase * 512 + d;
  const unsigned short* xc0 = xc_b + rbase * DIN + d;
  const unsigned short* zs0 = zsb + rbase * DIN + d;
  unsigned short* y0 = ydata + rbase * DIN + d;
  __syncthreads();
  for (int i = 0; i < CHL; ++i) {
    const float dt = b2f(dt0[(size_t)i * 512]);
    const float xt = b2f(xc0[(size_t)i * DIN]);
    const float zv = b2f(zs0[(size_t)i * DIN]);
    const float dtx = dt * xt;
    float dA[8];
    if (lin) {
      const float e1 = __expf(dt * An0g);
      const float e2 = e1*e1, e3 = e2*e1, e4 = e2*e2;
      const float e8 = e4*e4;
      const float st = e1 * (hf ? e8 : 1.f);
      dA[0]=st; dA[1]=st*e1; dA[2]=st*e2; dA[3]=st*e3;
      dA[4]=dA[0]*e4; dA[5]=dA[1]*e4; dA[6]=dA[2]*e4; dA[7]=dA[3]*e4;
    } else {
#pragma unroll
      for (int k = 0; k < 8; ++k) dA[k] = __expf(dt * An[k]);
    }
    const float* pr = &prs[i * 32];
    float4 B0 = *(const float4*)(pr + hf * 8);
    float4 B1 = *(const float4*)(pr + hf * 8 + 4);
    float4 C0 = *(const float4*)(pr + 16 + hf * 8);
    float4 C1 = *(const float4*)(pr + 16 + hf * 8 + 4);
    float ya = 0.f, yb = 0.f;
    h[0]=fmaf(dA[0],h[0],dtx*B0.x); ya=fmaf(h[0],C0.x,ya);
    h[1]=fmaf(dA[1],h[1],dtx*B0.y); yb=fmaf(h[1],C0.y,yb);
    h[2]=fmaf(dA[2],h[2],dtx*B0.z); ya=fmaf(h[2],C0.z,ya);
    h[3]=fmaf(dA[3],h[3],dtx*B0.w); yb=fmaf(h[3],C0.w,yb);
    h[4]=fmaf(dA[4],h[4],dtx*B1.x); ya=fmaf(h[4],C1.x,ya);
    h[5]=fmaf(dA[5],h[5],dtx*B1.y); yb=fmaf(h[5],C1.y,yb);
    h[6]=fmaf(dA[6],h[6],dtx*B1.z); ya=fmaf(h[6],C1.z,ya);
    h[7]=fmaf(dA[7],h[7],dtx*B1.w); yb=fmaf(h[7],C1.w,yb);
    float y = ya + yb;
    y += __shfl_xor(y, 1);
    if (!hf) {
      const float ov = (y + xt * dp) * zv;
      y0[(size_t)i * DIN] = f2b(ov);
    }
  }
}

// ---------------------------------------------------------------------------
// G4: outproj + residual(ub) -> padded channel-last bf16 xrp
// ---------------------------------------------------------------------------
__global__ __launch_bounds__(256)
void k_outproj_mfma(const unsigned short* __restrict__ ydata, const unsigned short* __restrict__ opwb,
                    const unsigned short* __restrict__ ub, unsigned short* __restrict__ xrp) {
  __shared__ __align__(16) unsigned short As[2][4096], Bs[2][4096];
  const int t = threadIdx.x, lane = t & 63, w = t >> 6;
  const int wm = w >> 1, wn = w & 1;
  const int b = blockIdx.z, m0 = blockIdx.y * 128, n0 = blockIdx.x * 128;
  f32x4 acc[4][4] = {};
  gemm_loop_128<512, 512, 512>(ydata + ((size_t)b * LHW + m0) * 512,
                               opwb + (size_t)n0 * 512, As, Bs, t, acc);
  const int fr = lane & 15, q4 = (lane >> 4) * 4;
#pragma unroll
  for (int i = 0; i < 4; ++i) {
    const int lbase = m0 + wm*64 + i*16 + q4;
#pragma unroll
    for (int q = 0; q < 4; ++q) {
      const int l = lbase + q;
      const int pos = ((l >> 6) + 1) * PW + (l & 63) + 1;
#pragma unroll
      for (int j = 0; j < 4; ++j) {
        const int o = n0 + wn*64 + j*16 + fr;
        const float r = b2f(ub[((size_t)b * LHW + l) * COUT + o]);
        xrp[((size_t)b * PPOS + pos) * COUT + o] = f2b(acc[i][j][q] + r);
      }
    }
  }
}

// ---------------------------------------------------------------------------
// G5: refine 3x3 conv, 128x128 tile, BK=128 (4 sub-slices/barrier), swizzled
// ---------------------------------------------------------------------------
__global__ __launch_bounds__(256)
void k_refine_mfma(const unsigned short* __restrict__ Aw,
                   const unsigned short* __restrict__ xrp,
                   const float* __restrict__ rb, const float* __restrict__ bng,
                   const float* __restrict__ bnb, const float* __restrict__ bnm,
                   const float* __restrict__ bnv, float* __restrict__ out) {
  __shared__ __align__(16) unsigned short As[4][4096], Bs[4][4096];
  const int t = threadIdx.x;
  const int lane = t & 63;
  const int w = t >> 6;
  const int wm = w >> 1, wn = w & 1;
  const int b  = blockIdx.z;
  const int m0 = blockIdx.y * 128;
  const int n0 = blockIdx.x * 128;
  const int y0 = n0 >> 6;
  const unsigned short* xb = xrp + (size_t)b * PPOS * COUT;
  const int arow = t >> 2;
  const int acol = (((t & 3) ^ ((t >> 3) & 3))) * 8;
  const int fr = lane & 15;
  const int g8 = ((lane >> 4) * 8) ^ (((fr >> 1) & 3) * 8);

#define RF_STAGE(ks, buf) {                                                            \
    const int tap_ = (ks) >> 3;                                                        \
    const int i0_  = ((ks) & 7) * 32;                                                  \
    const int ky_  = tap_ / 3, kx_ = tap_ - ky_ * 3;                                   \
    const int k0_  = tap_ * 256 + i0_;                                                 \
    const unsigned short* ga_ = Aw + (size_t)(m0 + arow) * 2304 + k0_ + acol;          \
    const unsigned short* gb_ = xb + ((size_t)((y0 + ky_) * PW + kx_ + arow)) * COUT + i0_ + acol; \
    gload16(ga_,              &As[buf][w * 512]);                                      \
    gload16(ga_ + 64 * 2304,  &As[buf][2048 + w * 512]);                               \
    gload16(gb_,              &Bs[buf][w * 512]);                                      \
    gload16(gb_ + PW * COUT,  &Bs[buf][2048 + w * 512]);                               \
  }

  f32x4 acc[4][4] = {};
  for (int ks = 0; ks < 72; ks += 4) {
    __syncthreads();
    RF_STAGE(ks, 0);
    RF_STAGE(ks + 1, 1);
    RF_STAGE(ks + 2, 2);
    RF_STAGE(ks + 3, 3);
    __syncthreads();
#pragma unroll
    for (int h = 0; h < 4; ++h) {
      bf16x8 af[4], bfr[4];
#pragma unroll
      for (int f = 0; f < 4; ++f) {
        af[f]  = *(const bf16x8*)&As[h][(wm*64 + f*16 + fr) * 32 + g8];
        bfr[f] = *(const bf16x8*)&Bs[h][(wn*64 + f*16 + fr) * 32 + g8];
      }
#pragma unroll
      for (int i = 0; i < 4; ++i)
#pragma unroll
        for (int j = 0; j < 4; ++j)
          acc[i][j] = __builtin_amdgcn_mfma_f32_16x16x32_bf16(af[i], bfr[j], acc[i][j], 0, 0, 0);
    }
  }
#undef RF_STAGE
  const int q4 = (lane >> 4) * 4;
#pragma unroll
  for (int i = 0; i < 4; ++i) {
    const int obase = m0 + wm*64 + i*16 + q4;
#pragma unroll
    for (int q = 0; q < 4; ++q) {
      const int o = obase + q;
      const float inv = bng[o] * rsqrtf(bnv[o] + 1e-5f);
      const float sh  = (rb[o] - bnm[o]) * inv + bnb[o];
      float* orow = out + ((size_t)b * COUT + o) * LHW + n0 + wn*64 + fr;
#pragma unroll
      for (int j = 0; j < 4; ++j)
        orow[j*16] = fmaxf(fmaf(acc[i][j][q], inv, sh), 0.f);
    }
  }
}

// ---------------------------------------------------------------------------
extern "C" void kernel_launch(void* const* d_in, const int* in_sizes, int n_in,
                              void* d_out, int out_size, void* d_ws, size_t ws_size,
                              hipStream_t stream) {
  const float* x    = (const float*)d_in[0];
  const float* lw   = (const float*)d_in[1];
  const float* lb   = (const float*)d_in[2];
  const float* ipw  = (const float*)d_in[3];
  const float* cw   = (const float*)d_in[4];
  const float* cb   = (const float*)d_in[5];
  const float* xpw  = (const float*)d_in[6];
  const float* dtpw = (const float*)d_in[7];
  const float* dtpb = (const float*)d_in[8];
  const float* Alog = (const float*)d_in[9];
  const float* Dpar = (const float*)d_in[10];
  const float* opw  = (const float*)d_in[11];
  const float* rw   = (const float*)d_in[12];
  const float* rb   = (const float*)d_in[13];
  const float* bng  = (const float*)d_in[14];
  const float* bnb  = (const float*)d_in[15];
  const float* bnm  = (const float*)d_in[16];
  const float* bnv  = (const float*)d_in[17];
  float* out = (float*)d_out;

  float* ws = (float*)d_ws;
  unsigned short* ub   = (unsigned short*)ws;                      // 8.4M us
  unsigned short* xt   = (unsigned short*)(ws + 4194304);          // 16.8M us (reused: dtb, xrp)
  unsigned short* xm_b = (unsigned short*)(ws + 12582912);         // 16.8M us (reused as ydata)
  unsigned short* xc_b = (unsigned short*)(ws + 20971520);         // 16.8M us
  unsigned short* zsb  = (unsigned short*)(ws + 29360128);         // 16.8M us
  float* proj = ws + 37748736;                                     //  1.57M f
  float* Sst  = ws + 39321600;                                     //  8.39M f
  float* SDT  = ws + 47710208;                                     //  0.52M f
  float* hst  = ws + 48234496;                                     //  8.39M f
  unsigned short* wb  = (unsigned short*)(ws + 64487424);          //  1.15M us
  unsigned short* wfb = (unsigned short*)(ws + 65060864);          //  0.33M us
  unsigned short* lwb  = wb;
  unsigned short* ipwb = wb + WO1;
  unsigned short* opwb = wb + WO3;
  unsigned short* Aw   = wb + WO4;
  unsigned short* ydata = xm_b;
  unsigned short* dtb   = xt;
  unsigned short* xrp   = xt;

  k_wprep<<<dim3(5760), 256, 0, stream>>>(lw, ipw, xpw, opw, rw, dtpw, wb, wfb);
  k_xpose<<<dim3(64, 8, 8), 256, 0, stream>>>(x, xt);
  k_lat_mfma<<<dim3(2, 32, 8), 256, 0, stream>>>(xt, lwb, lb, ub);
  k_inproj_mfma<<<dim3(8, 32, 8), 256, 0, stream>>>(ub, ipwb, xm_b, zsb);
  k_conv1d<<<dim3(1024), 256, 0, stream>>>(xm_b, cw, cb, xc_b);
  k_xdt_mfma<<<dim3(32, 5, 8), 256, 0, stream>>>(xc_b, wfb, dtpb, dtb, proj);
  k_scanA<<<dim3(NB * NCHK * 2), 512, 0, stream>>>(proj, dtb, xc_b, Alog, Sst, SDT);
  k_scanB<<<dim3(256), 256, 0, stream>>>(Sst, SDT, Alog, hst);
  k_scanC<<<dim3(NB * NCHK * 2), 512, 0, stream>>>(proj, dtb, xc_b, zsb, hst, Alog, Dpar, ydata);
  hipMemsetAsync(xrp, 0, (size_t)NB * PPOS * COUT * sizeof(unsigned short), stream);
  k_outproj_mfma<<<dim3(2, 32, 8), 256, 0, stream>>>(ydata, opwb, ub, xrp);
  k_refine_mfma<<<dim3(32, 2, 8), 256, 0, stream>>>(Aw, xrp, rb, bng, bnb, bnm, bnv, out);
}

// Round 14
// 343.419 us; speedup vs baseline: 1.0162x; 1.0162x over previous
//
#include <hip/hip_runtime.h>
#include <math.h>

#define NB   8
#define CIN  512
#define COUT 256
#define DIN  512
#define LHW  4096
#define NCHK 128
#define CHL  32
#define PW   66
#define PPOS (PW*PW)

typedef __attribute__((ext_vector_type(8))) short bf16x8;
typedef __attribute__((ext_vector_type(4))) float f32x4;
typedef __attribute__((ext_vector_type(2))) float f32x2;

__device__ __forceinline__ float siluf(float v)  { return v / (1.f + __expf(-v)); }
__device__ __forceinline__ float splusf(float v) {
  return fmaxf(v, 0.f) + __logf(1.f + __expf(-fabsf(v)));
}

__device__ __forceinline__ unsigned short f2b(float f) {
  union { float f; unsigned u; } v; v.f = f;
  unsigned r = v.u + 0x7fff + ((v.u >> 16) & 1);
  return (unsigned short)(r >> 16);
}
__device__ __forceinline__ float b2f(unsigned int u) {
  union { unsigned u; float f; } v; v.u = (u & 0xffffu) << 16; return v.f;
}

__device__ __forceinline__ f32x2 pk_fma(f32x2 a, f32x2 b, f32x2 c) {
  f32x2 d;
  asm("v_pk_fma_f32 %0, %1, %2, %3" : "=v"(d) : "v"(a), "v"(b), "v"(c));
  return d;
}
__device__ __forceinline__ f32x2 pk_mul(f32x2 a, f32x2 b) {
  f32x2 d;
  asm("v_pk_mul_f32 %0, %1, %2" : "=v"(d) : "v"(a), "v"(b));
  return d;
}

__device__ __forceinline__ void gload16(const unsigned short* g, unsigned short* l) {
  __builtin_amdgcn_global_load_lds(
      (const __attribute__((address_space(1))) unsigned int*)g,
      (__attribute__((address_space(3))) unsigned int*)l, 16, 0, 0);
}

// ---------------------------------------------------------------------------
// W: weight prep
// ---------------------------------------------------------------------------
#define WO1 131072
#define WO2 393216
#define WO3 425984
#define WO4 557056
#define WO5 1146880
__global__ __launch_bounds__(256)
void k_wprep(const float* __restrict__ lw, const float* __restrict__ ipw,
             const float* __restrict__ xpw, const float* __restrict__ opw,
             const float* __restrict__ rw, const float* __restrict__ dtpw,
             unsigned short* __restrict__ wb, unsigned short* __restrict__ wfb) {
  const int i = blockIdx.x * 256 + threadIdx.x;
  if (i < WO1)      wb[i] = f2b(lw[i]);
  else if (i < WO2) wb[i] = f2b(ipw[i - WO1]);
  else if (i < WO3) {
    const int j = i - WO2, row = j >> 9, col = j & 511;
    wb[i] = (row < 48) ? f2b(xpw[row * 512 + col]) : (unsigned short)0;
  }
  else if (i < WO4) wb[i] = f2b(opw[i - WO3]);
  else if (i < WO5) {
    const int j = i - WO4, o = j / 2304, kk = j % 2304;
    const int tap = kk >> 8, ch = kk & 255;
    wb[i] = f2b(rw[(o * 256 + ch) * 9 + tap]);
  }
  else {
    const int j = i - WO5, row = j >> 9, e = j & 511;
    float v = 0.f;
    if (row < 512) {
#pragma unroll
      for (int r = 0; r < 16; ++r)
        v = fmaf(dtpw[row * 16 + r], xpw[r * 512 + e], v);
    } else if (row < 560) {
      v = xpw[(row - 512) * 512 + e];
    }
    wfb[j] = f2b(v);
  }
}

// ---------------------------------------------------------------------------
// T: transpose x (b,k,l) f32 -> xt (b,l,k) bf16
// ---------------------------------------------------------------------------
__global__ __launch_bounds__(256)
void k_xpose(const float* __restrict__ x, unsigned short* __restrict__ xt) {
  __shared__ unsigned short Ts[64][80];
  const int b  = blockIdx.z;
  const int k0 = blockIdx.y * 64;
  const int l0 = blockIdx.x * 64;
  const int t  = threadIdx.x;
  const int tx = t & 15, ty = t >> 4;
#pragma unroll
  for (int r = 0; r < 4; ++r) {
    const int k = ty + r * 16;
    float4 v = *(const float4*)(x + ((size_t)b * CIN + k0 + k) * LHW + l0 + tx * 4);
    Ts[tx*4+0][k] = f2b(v.x);
    Ts[tx*4+1][k] = f2b(v.y);
    Ts[tx*4+2][k] = f2b(v.z);
    Ts[tx*4+3][k] = f2b(v.w);
  }
  __syncthreads();
  const int lr = t >> 2, kc = (t & 3) * 16;
  unsigned short* dst = xt + ((size_t)b * LHW + l0 + lr) * CIN + k0 + kc;
  *(uint4*)dst       = *(const uint4*)&Ts[lr][kc];
  *(uint4*)(dst + 8) = *(const uint4*)&Ts[lr][kc + 8];
}

// ---------------------------------------------------------------------------
// shared MFMA main loop: 128x128 tile, BK=64 + XOR-swizzled LDS (R12-proven)
// ---------------------------------------------------------------------------
template<int RSA, int RSB, int KTOT>
__device__ __forceinline__ void gemm_loop_128(
    const unsigned short* __restrict__ Ab, const unsigned short* __restrict__ Bb,
    unsigned short (&As)[2][4096], unsigned short (&Bs)[2][4096],
    int t, f32x4 acc[4][4]) {
  const int w = t >> 6, lane = t & 63;
  const int wm = w >> 1, wn = w & 1;
  const int arow = t >> 2;
  const int acol = (((t & 3) ^ ((t >> 3) & 3))) * 8;
  const int fr = lane & 15;
  const int g8 = ((lane >> 4) * 8) ^ (((fr >> 1) & 3) * 8);
  for (int k0 = 0; k0 < KTOT; k0 += 64) {
    __syncthreads();
    gload16(Ab + (size_t)arow * RSA + k0 + acol,             &As[0][w * 512]);
    gload16(Ab + (size_t)(64 + arow) * RSA + k0 + acol,      &As[0][2048 + w*512]);
    gload16(Bb + (size_t)arow * RSB + k0 + acol,             &Bs[0][w * 512]);
    gload16(Bb + (size_t)(64 + arow) * RSB + k0 + acol,      &Bs[0][2048 + w*512]);
    gload16(Ab + (size_t)arow * RSA + k0 + 32 + acol,        &As[1][w * 512]);
    gload16(Ab + (size_t)(64 + arow) * RSA + k0 + 32 + acol, &As[1][2048 + w*512]);
    gload16(Bb + (size_t)arow * RSB + k0 + 32 + acol,        &Bs[1][w * 512]);
    gload16(Bb + (size_t)(64 + arow) * RSB + k0 + 32 + acol, &Bs[1][2048 + w*512]);
    __syncthreads();
#pragma unroll
    for (int h = 0; h < 2; ++h) {
      bf16x8 af[4], bf[4];
#pragma unroll
      for (int f = 0; f < 4; ++f) {
        af[f] = *(const bf16x8*)&As[h][(wm*64 + f*16 + fr) * 32 + g8];
        bf[f] = *(const bf16x8*)&Bs[h][(wn*64 + f*16 + fr) * 32 + g8];
      }
#pragma unroll
      for (int i = 0; i < 4; ++i)
#pragma unroll
        for (int j = 0; j < 4; ++j)
          acc[i][j] = __builtin_amdgcn_mfma_f32_16x16x32_bf16(af[i], bf[j], acc[i][j], 0, 0, 0);
    }
  }
}

// ---------------------------------------------------------------------------
// G1: lateral
// ---------------------------------------------------------------------------
__global__ __launch_bounds__(256)
void k_lat_mfma(const unsigned short* __restrict__ xt, const unsigned short* __restrict__ lwb,
                const float* __restrict__ lb, unsigned short* __restrict__ ub) {
  __shared__ __align__(16) unsigned short As[2][4096], Bs[2][4096];
  const int t = threadIdx.x, lane = t & 63, w = t >> 6;
  const int wm = w >> 1, wn = w & 1;
  const int b = blockIdx.z, m0 = blockIdx.y * 128, n0 = blockIdx.x * 128;
  f32x4 acc[4][4] = {};
  gemm_loop_128<512, 512, 512>(xt + ((size_t)b * LHW + m0) * 512,
                               lwb + (size_t)n0 * 512, As, Bs, t, acc);
  const int fr = lane & 15, q4 = (lane >> 4) * 4;
#pragma unroll
  for (int i = 0; i < 4; ++i) {
    const int l = m0 + wm*64 + i*16 + q4;
#pragma unroll
    for (int j = 0; j < 4; ++j) {
      const int o = n0 + wn*64 + j*16 + fr;
      const float bias = lb[o];
      unsigned short* dst = ub + ((size_t)b * LHW + l) * COUT + o;
#pragma unroll
      for (int q = 0; q < 4; ++q)
        dst[(size_t)q * COUT] = f2b(acc[i][j][q] + bias);
    }
  }
}

// ---------------------------------------------------------------------------
// G2: inproj
// ---------------------------------------------------------------------------
__global__ __launch_bounds__(256)
void k_inproj_mfma(const unsigned short* __restrict__ ub, const unsigned short* __restrict__ ipwb,
                   unsigned short* __restrict__ xm_b, unsigned short* __restrict__ zsb) {
  __shared__ __align__(16) unsigned short As[2][4096], Bs[2][4096];
  const int t = threadIdx.x, lane = t & 63, w = t >> 6;
  const int wm = w >> 1, wn = w & 1;
  const int b = blockIdx.z, m0 = blockIdx.y * 128, n0 = blockIdx.x * 128;
  f32x4 acc[4][4] = {};
  gemm_loop_128<256, 256, 256>(ub + ((size_t)b * LHW + m0) * 256,
                               ipwb + (size_t)n0 * 256, As, Bs, t, acc);
  const int fr = lane & 15, q4 = (lane >> 4) * 4;
  const bool isz = (n0 >= 512);
#pragma unroll
  for (int i = 0; i < 4; ++i) {
    const int l = m0 + wm*64 + i*16 + q4;
#pragma unroll
    for (int j = 0; j < 4; ++j) {
      const int e = n0 + wn*64 + j*16 + fr;
      if (isz) {
        unsigned short* dst = zsb + ((size_t)b * LHW + l) * DIN + (e - 512);
#pragma unroll
        for (int q = 0; q < 4; ++q)
          dst[(size_t)q * DIN] = f2b(siluf(acc[i][j][q]));
      } else {
        unsigned short* dst = xm_b + ((size_t)b * LHW + l) * DIN + e;
#pragma unroll
        for (int q = 0; q < 4; ++q)
          dst[(size_t)q * DIN] = f2b(acc[i][j][q]);
      }
    }
  }
}

// ---------------------------------------------------------------------------
// K3: depthwise causal conv1d, 8 rows/thread
// ---------------------------------------------------------------------------
__global__ __launch_bounds__(256)
void k_conv1d(const unsigned short* __restrict__ xm_b, const float* __restrict__ cw,
              const float* __restrict__ cb, unsigned short* __restrict__ xc_b) {
  const int tid = blockIdx.x * 256 + threadIdx.x;
  const int e8 = tid & 63;
  const int lg = tid >> 6;
  const int l0 = (lg & 511) * 8;
  const int b  = lg >> 9;
  const int e0 = e8 * 8;
  float bias[8];
  *(float4*)&bias[0] = *(const float4*)(cb + e0);
  *(float4*)&bias[4] = *(const float4*)(cb + e0 + 4);
  float wv[8][4];
#pragma unroll
  for (int q = 0; q < 8; ++q) {
    float4 w4 = *(const float4*)(cw + (e0 + q) * 4);
    wv[q][0] = w4.x; wv[q][1] = w4.y; wv[q][2] = w4.z; wv[q][3] = w4.w;
  }
  const unsigned short* base = xm_b + ((size_t)b * LHW + l0) * DIN + e0;
  uint4 rows[11];
  const uint4 z4 = make_uint4(0u, 0u, 0u, 0u);
#pragma unroll
  for (int r = 0; r < 11; ++r) {
    const int ll = r - 3;
    rows[r] = (l0 + ll >= 0) ? *(const uint4*)(base + (ptrdiff_t)ll * DIN) : z4;
  }
  unsigned short* outb = xc_b + ((size_t)b * LHW + l0) * DIN + e0;
#pragma unroll
  for (int j = 0; j < 8; ++j) {
    float acc[8];
#pragma unroll
    for (int q = 0; q < 8; ++q) acc[q] = bias[q];
#pragma unroll
    for (int k = 0; k < 4; ++k) {
      const uint4 raw = rows[j + k];
      acc[0] = fmaf(b2f(raw.x),       wv[0][k], acc[0]);
      acc[1] = fmaf(b2f(raw.x >> 16), wv[1][k], acc[1]);
      acc[2] = fmaf(b2f(raw.y),       wv[2][k], acc[2]);
      acc[3] = fmaf(b2f(raw.y >> 16), wv[3][k], acc[3]);
      acc[4] = fmaf(b2f(raw.z),       wv[4][k], acc[4]);
      acc[5] = fmaf(b2f(raw.z >> 16), wv[5][k], acc[5]);
      acc[6] = fmaf(b2f(raw.w),       wv[6][k], acc[6]);
      acc[7] = fmaf(b2f(raw.w >> 16), wv[7][k], acc[7]);
    }
    uint4 o;
    o.x = (unsigned)f2b(siluf(acc[0])) | ((unsigned)f2b(siluf(acc[1])) << 16);
    o.y = (unsigned)f2b(siluf(acc[2])) | ((unsigned)f2b(siluf(acc[3])) << 16);
    o.z = (unsigned)f2b(siluf(acc[4])) | ((unsigned)f2b(siluf(acc[5])) << 16);
    o.w = (unsigned)f2b(siluf(acc[6])) | ((unsigned)f2b(siluf(acc[7])) << 16);
    *(uint4*)(outb + (size_t)j * DIN) = o;
  }
}

// ---------------------------------------------------------------------------
// G3: fused xproj+dt GEMM
// ---------------------------------------------------------------------------
__global__ __launch_bounds__(256)
void k_xdt_mfma(const unsigned short* __restrict__ xc_b, const unsigned short* __restrict__ wfb,
                const float* __restrict__ dtpb,
                unsigned short* __restrict__ dtb, float* __restrict__ proj) {
  __shared__ __align__(16) unsigned short As[2][4096], Bs[2][4096];
  const int t = threadIdx.x, lane = t & 63, w = t >> 6;
  const int wm = w >> 1, wn = w & 1;
  const int b = blockIdx.z, m0 = blockIdx.x * 128, n0 = blockIdx.y * 128;
  f32x4 acc[4][4] = {};
  gemm_loop_128<512, 512, 512>(xc_b + ((size_t)b * LHW + m0) * 512,
                               wfb + (size_t)n0 * 512, As, Bs, t, acc);
  const int fr = lane & 15, q4 = (lane >> 4) * 4;
#pragma unroll
  for (int i = 0; i < 4; ++i) {
    const int l = m0 + wm*64 + i*16 + q4;
#pragma unroll
    for (int j = 0; j < 4; ++j) {
      const int c = n0 + wn*64 + j*16 + fr;
      if (c < 512) {
        const float bias = dtpb[c];
        unsigned short* dst = dtb + ((size_t)b * LHW + l) * 512 + c;
#pragma unroll
        for (int q = 0; q < 4; ++q)
          dst[(size_t)q * 512] = f2b(splusf(acc[i][j][q] + bias));
      } else if (c < 560) {
        float* dst = proj + ((size_t)b * LHW + l) * 48 + (c - 512);
#pragma unroll
        for (int q = 0; q < 4; ++q)
          dst[(size_t)q * 48] = acc[i][j][q];
      }
    }
  }
}

// ---------------------------------------------------------------------------
// K5: scan phase A — 1 thread per d, 16 states, packed-f32 math.
// Outputs: Sst (local end states), SDT (sum dt per chunk-d)
// ---------------------------------------------------------------------------
__global__ __launch_bounds__(512, 4)
void k_scanA(const float* __restrict__ proj, const unsigned short* __restrict__ dtb,
             const unsigned short* __restrict__ xc_b, const float* __restrict__ A_log,
             float* __restrict__ Sst, float* __restrict__ SDT) {
  __shared__ float prs[CHL * 16];
  const int bx = blockIdx.x;                 // chunkid
  const int b = bx >> 7, c = bx & 127;
  const int d = threadIdx.x;
  const size_t rbase = (size_t)b * LHW + c * CHL;
  for (int i = d; i < CHL * 4; i += 512) {
    const int row = i >> 2, c4 = i & 3;
    *(float4*)&prs[row * 16 + c4 * 4] = *(const float4*)(proj + (rbase + row) * 48 + 16 + c4 * 4);
  }
  float An[16];
#pragma unroll
  for (int q = 0; q < 4; ++q) {
    float4 a4 = *(const float4*)(A_log + d*16 + q*4);
    An[q*4+0] = -__expf(a4.x); An[q*4+1] = -__expf(a4.y);
    An[q*4+2] = -__expf(a4.z); An[q*4+3] = -__expf(a4.w);
  }
  f32x2 h2[8];
#pragma unroll
  for (int k = 0; k < 8; ++k) h2[k] = (f32x2){0.f, 0.f};
  const float An0 = An[0];
  bool lin = true;
#pragma unroll
  for (int n = 1; n < 16; ++n)
    lin = lin && (fabsf(An[n] - (n + 1) * An0) <= 1e-4f * fabsf(An[n]));
  float sdt = 0.f;
  const unsigned short* dt0 = dtb + rbase * 512 + d;
  const unsigned short* xc0 = xc_b + rbase * DIN + d;
  __syncthreads();
  for (int i = 0; i < CHL; ++i) {
    const float dt = b2f(dt0[(size_t)i * 512]);
    sdt += dt;
    const float dtx = dt * b2f(xc0[(size_t)i * DIN]);
    const f32x2 dtx2 = (f32x2){dtx, dtx};
    f32x2 dA2[8];
    if (lin) {
      const float e1 = __expf(dt * An0);
      const float e2 = e1*e1, e3 = e2*e1, e4 = e2*e2, e8 = e4*e4;
      const f32x2 e4v = (f32x2){e4, e4}, e8v = (f32x2){e8, e8};
      dA2[0] = (f32x2){e1, e2};
      dA2[1] = (f32x2){e3, e4};
      dA2[2] = pk_mul(dA2[0], e4v);
      dA2[3] = pk_mul(dA2[1], e4v);
      dA2[4] = pk_mul(dA2[0], e8v);
      dA2[5] = pk_mul(dA2[1], e8v);
      dA2[6] = pk_mul(dA2[2], e8v);
      dA2[7] = pk_mul(dA2[3], e8v);
    } else {
#pragma unroll
      for (int k = 0; k < 8; ++k)
        dA2[k] = (f32x2){__expf(dt * An[2*k]), __expf(dt * An[2*k+1])};
    }
    const f32x2* B2 = (const f32x2*)&prs[i * 16];
#pragma unroll
    for (int k = 0; k < 8; ++k)
      h2[k] = pk_fma(dA2[k], h2[k], pk_mul(dtx2, B2[k]));
  }
  float* o = Sst + ((size_t)bx * 512 + d) * 16;
#pragma unroll
  for (int k = 0; k < 4; ++k)
    *(float4*)(o + k*4) = make_float4(h2[2*k].x, h2[2*k].y, h2[2*k+1].x, h2[2*k+1].y);
  SDT[(size_t)bx * 512 + d] = sdt;
}

// ---------------------------------------------------------------------------
// K6: scan phase B — combine chunk summaries (P reconstructed from SDT)
// ---------------------------------------------------------------------------
__global__ __launch_bounds__(256)
void k_scanB(const float* __restrict__ Sst, const float* __restrict__ SDT,
             const float* __restrict__ A_log, float* __restrict__ hst) {
  const int tid = blockIdx.x * 256 + threadIdx.x;
  const int n = tid & 15;
  const int d = (tid >> 4) & 511;
  const int b = tid >> 13;
  const float An = -__expf(A_log[d * 16 + n]);
  float h = 0.f;
  for (int c = 0; c < NCHK; ++c) {
    const size_t idx = (size_t)((b*NCHK + c)*512 + d);
    hst[idx*16 + n] = h;
    h = __expf(SDT[idx] * An) * h + Sst[idx*16 + n];
  }
}

// ---------------------------------------------------------------------------
// K7: scan phase C — 1 thread per d, 16 states, packed-f32 math
// ---------------------------------------------------------------------------
__global__ __launch_bounds__(512, 4)
void k_scanC(const float* __restrict__ proj, const unsigned short* __restrict__ dtb,
             const unsigned short* __restrict__ xc_b,
             const unsigned short* __restrict__ zsb, const float* __restrict__ hst,
             const float* __restrict__ A_log, const float* __restrict__ Dpar,
             unsigned short* __restrict__ ydata) {
  __shared__ float prs[CHL * 32];
  const int bx = blockIdx.x;                 // chunkid
  const int b = bx >> 7, c = bx & 127;
  const int d = threadIdx.x;
  const size_t rbase = (size_t)b * LHW + c * CHL;
  for (int i = d; i < CHL * 8; i += 512) {
    const int row = i >> 3, c4 = i & 7;
    *(float4*)&prs[row * 32 + c4 * 4] = *(const float4*)(proj + (rbase + row) * 48 + 16 + c4 * 4);
  }
  float An[16];
#pragma unroll
  for (int q = 0; q < 4; ++q) {
    float4 a4 = *(const float4*)(A_log + d*16 + q*4);
    An[q*4+0] = -__expf(a4.x); An[q*4+1] = -__expf(a4.y);
    An[q*4+2] = -__expf(a4.z); An[q*4+3] = -__expf(a4.w);
  }
  f32x2 h2[8];
  {
    const float* hsrc = hst + ((size_t)bx * 512 + d) * 16;
#pragma unroll
    for (int k = 0; k < 8; ++k)
      h2[k] = *(const f32x2*)(hsrc + 2*k);
  }
  const float An0 = An[0];
  bool lin = true;
#pragma unroll
  for (int n = 1; n < 16; ++n)
    lin = lin && (fabsf(An[n] - (n + 1) * An0) <= 1e-4f * fabsf(An[n]));
  const float dp = Dpar[d];
  const unsigned short* dt0 = dtb + rbase * 512 + d;
  const unsigned short* xc0 = xc_b + rbase * DIN + d;
  const unsigned short* zs0 = zsb + rbase * DIN + d;
  unsigned short* y0 = ydata + rbase * DIN + d;
  __syncthreads();
  for (int i = 0; i < CHL; ++i) {
    const float dt = b2f(dt0[(size_t)i * 512]);
    const float xt = b2f(xc0[(size_t)i * DIN]);
    const float zv = b2f(zs0[(size_t)i * DIN]);
    const float dtx = dt * xt;
    const f32x2 dtx2 = (f32x2){dtx, dtx};
    f32x2 dA2[8];
    if (lin) {
      const float e1 = __expf(dt * An0);
      const float e2 = e1*e1, e3 = e2*e1, e4 = e2*e2, e8 = e4*e4;
      const f32x2 e4v = (f32x2){e4, e4}, e8v = (f32x2){e8, e8};
      dA2[0] = (f32x2){e1, e2};
      dA2[1] = (f32x2){e3, e4};
      dA2[2] = pk_mul(dA2[0], e4v);
      dA2[3] = pk_mul(dA2[1], e4v);
      dA2[4] = pk_mul(dA2[0], e8v);
      dA2[5] = pk_mul(dA2[1], e8v);
      dA2[6] = pk_mul(dA2[2], e8v);
      dA2[7] = pk_mul(dA2[3], e8v);
    } else {
#pragma unroll
      for (int k = 0; k < 8; ++k)
        dA2[k] = (f32x2){__expf(dt * An[2*k]), __expf(dt * An[2*k+1])};
    }
    const f32x2* B2 = (const f32x2*)&prs[i * 32];
    const f32x2* C2 = (const f32x2*)&prs[i * 32 + 16];
    f32x2 ya = (f32x2){0.f, 0.f}, yb = (f32x2){0.f, 0.f};
#pragma unroll
    for (int k = 0; k < 8; ++k) {
      h2[k] = pk_fma(dA2[k], h2[k], pk_mul(dtx2, B2[k]));
      if (k & 1) yb = pk_fma(h2[k], C2[k], yb);
      else       ya = pk_fma(h2[k], C2[k], ya);
    }
    const float y = (ya.x + ya.y) + (yb.x + yb.y);
    const float ov = (y + xt * dp) * zv;
    y0[(size_t)i * DIN] = f2b(ov);
  }
}

// ---------------------------------------------------------------------------
// G4: outproj + residual(ub) -> padded channel-last bf16 xrp
// ---------------------------------------------------------------------------
__global__ __launch_bounds__(256)
void k_outproj_mfma(const unsigned short* __restrict__ ydata, const unsigned short* __restrict__ opwb,
                    const unsigned short* __restrict__ ub, unsigned short* __restrict__ xrp) {
  __shared__ __align__(16) unsigned short As[2][4096], Bs[2][4096];
  const int t = threadIdx.x, lane = t & 63, w = t >> 6;
  const int wm = w >> 1, wn = w & 1;
  const int b = blockIdx.z, m0 = blockIdx.y * 128, n0 = blockIdx.x * 128;
  f32x4 acc[4][4] = {};
  gemm_loop_128<512, 512, 512>(ydata + ((size_t)b * LHW + m0) * 512,
                               opwb + (size_t)n0 * 512, As, Bs, t, acc);
  const int fr = lane & 15, q4 = (lane >> 4) * 4;
#pragma unroll
  for (int i = 0; i < 4; ++i) {
    const int lbase = m0 + wm*64 + i*16 + q4;
#pragma unroll
    for (int q = 0; q < 4; ++q) {
      const int l = lbase + q;
      const int pos = ((l >> 6) + 1) * PW + (l & 63) + 1;
#pragma unroll
      for (int j = 0; j < 4; ++j) {
        const int o = n0 + wn*64 + j*16 + fr;
        const float r = b2f(ub[((size_t)b * LHW + l) * COUT + o]);
        xrp[((size_t)b * PPOS + pos) * COUT + o] = f2b(acc[i][j][q] + r);
      }
    }
  }
}

// ---------------------------------------------------------------------------
// G5: refine 3x3 conv, 128x128 tile, BK=128 (4 sub-slices/barrier), swizzled
// ---------------------------------------------------------------------------
__global__ __launch_bounds__(256)
void k_refine_mfma(const unsigned short* __restrict__ Aw,
                   const unsigned short* __restrict__ xrp,
                   const float* __restrict__ rb, const float* __restrict__ bng,
                   const float* __restrict__ bnb, const float* __restrict__ bnm,
                   const float* __restrict__ bnv, float* __restrict__ out) {
  __shared__ __align__(16) unsigned short As[4][4096], Bs[4][4096];
  const int t = threadIdx.x;
  const int lane = t & 63;
  const int w = t >> 6;
  const int wm = w >> 1, wn = w & 1;
  const int b  = blockIdx.z;
  const int m0 = blockIdx.y * 128;
  const int n0 = blockIdx.x * 128;
  const int y0 = n0 >> 6;
  const unsigned short* xb = xrp + (size_t)b * PPOS * COUT;
  const int arow = t >> 2;
  const int acol = (((t & 3) ^ ((t >> 3) & 3))) * 8;
  const int fr = lane & 15;
  const int g8 = ((lane >> 4) * 8) ^ (((fr >> 1) & 3) * 8);

#define RF_STAGE(ks, buf) {                                                            \
    const int tap_ = (ks) >> 3;                                                        \
    const int i0_  = ((ks) & 7) * 32;                                                  \
    const int ky_  = tap_ / 3, kx_ = tap_ - ky_ * 3;                                   \
    const int k0_  = tap_ * 256 + i0_;                                                 \
    const unsigned short* ga_ = Aw + (size_t)(m0 + arow) * 2304 + k0_ + acol;          \
    const unsigned short* gb_ = xb + ((size_t)((y0 + ky_) * PW + kx_ + arow)) * COUT + i0_ + acol; \
    gload16(ga_,              &As[buf][w * 512]);                                      \
    gload16(ga_ + 64 * 2304,  &As[buf][2048 + w * 512]);                               \
    gload16(gb_,              &Bs[buf][w * 512]);                                      \
    gload16(gb_ + PW * COUT,  &Bs[buf][2048 + w * 512]);                               \
  }

  f32x4 acc[4][4] = {};
  for (int ks = 0; ks < 72; ks += 4) {
    __syncthreads();
    RF_STAGE(ks, 0);
    RF_STAGE(ks + 1, 1);
    RF_STAGE(ks + 2, 2);
    RF_STAGE(ks + 3, 3);
    __syncthreads();
#pragma unroll
    for (int h = 0; h < 4; ++h) {
      bf16x8 af[4], bfr[4];
#pragma unroll
      for (int f = 0; f < 4; ++f) {
        af[f]  = *(const bf16x8*)&As[h][(wm*64 + f*16 + fr) * 32 + g8];
        bfr[f] = *(const bf16x8*)&Bs[h][(wn*64 + f*16 + fr) * 32 + g8];
      }
#pragma unroll
      for (int i = 0; i < 4; ++i)
#pragma unroll
        for (int j = 0; j < 4; ++j)
          acc[i][j] = __builtin_amdgcn_mfma_f32_16x16x32_bf16(af[i], bfr[j], acc[i][j], 0, 0, 0);
    }
  }
#undef RF_STAGE
  const int q4 = (lane >> 4) * 4;
#pragma unroll
  for (int i = 0; i < 4; ++i) {
    const int obase = m0 + wm*64 + i*16 + q4;
#pragma unroll
    for (int q = 0; q < 4; ++q) {
      const int o = obase + q;
      const float inv = bng[o] * rsqrtf(bnv[o] + 1e-5f);
      const float sh  = (rb[o] - bnm[o]) * inv + bnb[o];
      float* orow = out + ((size_t)b * COUT + o) * LHW + n0 + wn*64 + fr;
#pragma unroll
      for (int j = 0; j < 4; ++j)
        orow[j*16] = fmaxf(fmaf(acc[i][j][q], inv, sh), 0.f);
    }
  }
}

// ---------------------------------------------------------------------------
extern "C" void kernel_launch(void* const* d_in, const int* in_sizes, int n_in,
                              void* d_out, int out_size, void* d_ws, size_t ws_size,
                              hipStream_t stream) {
  const float* x    = (const float*)d_in[0];
  const float* lw   = (const float*)d_in[1];
  const float* lb   = (const float*)d_in[2];
  const float* ipw  = (const float*)d_in[3];
  const float* cw   = (const float*)d_in[4];
  const float* cb   = (const float*)d_in[5];
  const float* xpw  = (const float*)d_in[6];
  const float* dtpw = (const float*)d_in[7];
  const float* dtpb = (const float*)d_in[8];
  const float* Alog = (const float*)d_in[9];
  const float* Dpar = (const float*)d_in[10];
  const float* opw  = (const float*)d_in[11];
  const float* rw   = (const float*)d_in[12];
  const float* rb   = (const float*)d_in[13];
  const float* bng  = (const float*)d_in[14];
  const float* bnb  = (const float*)d_in[15];
  const float* bnm  = (const float*)d_in[16];
  const float* bnv  = (const float*)d_in[17];
  float* out = (float*)d_out;

  float* ws = (float*)d_ws;
  unsigned short* ub   = (unsigned short*)ws;                      // 8.4M us
  unsigned short* xt   = (unsigned short*)(ws + 4194304);          // 16.8M us (reused: dtb, xrp)
  unsigned short* xm_b = (unsigned short*)(ws + 12582912);         // 16.8M us (reused as ydata)
  unsigned short* xc_b = (unsigned short*)(ws + 20971520);         // 16.8M us
  unsigned short* zsb  = (unsigned short*)(ws + 29360128);         // 16.8M us
  float* proj = ws + 37748736;                                     //  1.57M f
  float* Sst  = ws + 39321600;                                     //  8.39M f
  float* SDT  = ws + 47710208;                                     //  0.52M f
  float* hst  = ws + 48234496;                                     //  8.39M f
  unsigned short* wb  = (unsigned short*)(ws + 64487424);          //  1.15M us
  unsigned short* wfb = (unsigned short*)(ws + 65060864);          //  0.33M us
  unsigned short* lwb  = wb;
  unsigned short* ipwb = wb + WO1;
  unsigned short* opwb = wb + WO3;
  unsigned short* Aw   = wb + WO4;
  unsigned short* ydata = xm_b;
  unsigned short* dtb   = xt;
  unsigned short* xrp   = xt;

  k_wprep<<<dim3(5760), 256, 0, stream>>>(lw, ipw, xpw, opw, rw, dtpw, wb, wfb);
  k_xpose<<<dim3(64, 8, 8), 256, 0, stream>>>(x, xt);
  k_lat_mfma<<<dim3(2, 32, 8), 256, 0, stream>>>(xt, lwb, lb, ub);
  k_inproj_mfma<<<dim3(8, 32, 8), 256, 0, stream>>>(ub, ipwb, xm_b, zsb);
  k_conv1d<<<dim3(1024), 256, 0, stream>>>(xm_b, cw, cb, xc_b);
  k_xdt_mfma<<<dim3(32, 5, 8), 256, 0, stream>>>(xc_b, wfb, dtpb, dtb, proj);
  k_scanA<<<dim3(NB * NCHK), 512, 0, stream>>>(proj, dtb, xc_b, Alog, Sst, SDT);
  k_scanB<<<dim3(256), 256, 0, stream>>>(Sst, SDT, Alog, hst);
  k_scanC<<<dim3(NB * NCHK), 512, 0, stream>>>(proj, dtb, xc_b, zsb, hst, Alog, Dpar, ydata);
  hipMemsetAsync(xrp, 0, (size_t)NB * PPOS * COUT * sizeof(unsigned short), stream);
  k_outproj_mfma<<<dim3(2, 32, 8), 256, 0, stream>>>(ydata, opwb, ub, xrp);
  k_refine_mfma<<<dim3(32, 2, 8), 256, 0, stream>>>(Aw, xrp, rb, bng, bnb, bnm, bnv, out);
}

// Round 15
// 336.389 us; speedup vs baseline: 1.0375x; 1.0209x over previous
//
#include <hip/hip_runtime.h>
#include <math.h>

#define NB   8
#define CIN  512
#define COUT 256
#define DIN  512
#define LHW  4096
#define NCHK 256
#define CHL  16
#define PW   66
#define PPOS (PW*PW)

typedef __attribute__((ext_vector_type(8))) short bf16x8;
typedef __attribute__((ext_vector_type(4))) float f32x4;
typedef __attribute__((ext_vector_type(2))) float f32x2;

__device__ __forceinline__ float siluf(float v)  { return v / (1.f + __expf(-v)); }
__device__ __forceinline__ float splusf(float v) {
  return fmaxf(v, 0.f) + __logf(1.f + __expf(-fabsf(v)));
}

__device__ __forceinline__ unsigned short f2b(float f) {
  union { float f; unsigned u; } v; v.f = f;
  unsigned r = v.u + 0x7fff + ((v.u >> 16) & 1);
  return (unsigned short)(r >> 16);
}
__device__ __forceinline__ float b2f(unsigned int u) {
  union { unsigned u; float f; } v; v.u = (u & 0xffffu) << 16; return v.f;
}

__device__ __forceinline__ f32x2 pk_fma(f32x2 a, f32x2 b, f32x2 c) {
  f32x2 d;
  asm("v_pk_fma_f32 %0, %1, %2, %3" : "=v"(d) : "v"(a), "v"(b), "v"(c));
  return d;
}
__device__ __forceinline__ f32x2 pk_mul(f32x2 a, f32x2 b) {
  f32x2 d;
  asm("v_pk_mul_f32 %0, %1, %2" : "=v"(d) : "v"(a), "v"(b));
  return d;
}

__device__ __forceinline__ void gload16(const unsigned short* g, unsigned short* l) {
  __builtin_amdgcn_global_load_lds(
      (const __attribute__((address_space(1))) unsigned int*)g,
      (__attribute__((address_space(3))) unsigned int*)l, 16, 0, 0);
}

// ---------------------------------------------------------------------------
// W: weight prep
// ---------------------------------------------------------------------------
#define WO1 131072
#define WO2 393216
#define WO3 425984
#define WO4 557056
#define WO5 1146880
__global__ __launch_bounds__(256)
void k_wprep(const float* __restrict__ lw, const float* __restrict__ ipw,
             const float* __restrict__ xpw, const float* __restrict__ opw,
             const float* __restrict__ rw, const float* __restrict__ dtpw,
             unsigned short* __restrict__ wb, unsigned short* __restrict__ wfb) {
  const int i = blockIdx.x * 256 + threadIdx.x;
  if (i < WO1)      wb[i] = f2b(lw[i]);
  else if (i < WO2) wb[i] = f2b(ipw[i - WO1]);
  else if (i < WO3) {
    const int j = i - WO2, row = j >> 9, col = j & 511;
    wb[i] = (row < 48) ? f2b(xpw[row * 512 + col]) : (unsigned short)0;
  }
  else if (i < WO4) wb[i] = f2b(opw[i - WO3]);
  else if (i < WO5) {
    const int j = i - WO4, o = j / 2304, kk = j % 2304;
    const int tap = kk >> 8, ch = kk & 255;
    wb[i] = f2b(rw[(o * 256 + ch) * 9 + tap]);
  }
  else {
    const int j = i - WO5, row = j >> 9, e = j & 511;
    float v = 0.f;
    if (row < 512) {
#pragma unroll
      for (int r = 0; r < 16; ++r)
        v = fmaf(dtpw[row * 16 + r], xpw[r * 512 + e], v);
    } else if (row < 560) {
      v = xpw[(row - 512) * 512 + e];
    }
    wfb[j] = f2b(v);
  }
}

// ---------------------------------------------------------------------------
// T: transpose x (b,k,l) f32 -> xt (b,l,k) bf16
// ---------------------------------------------------------------------------
__global__ __launch_bounds__(256)
void k_xpose(const float* __restrict__ x, unsigned short* __restrict__ xt) {
  __shared__ unsigned short Ts[64][80];
  const int b  = blockIdx.z;
  const int k0 = blockIdx.y * 64;
  const int l0 = blockIdx.x * 64;
  const int t  = threadIdx.x;
  const int tx = t & 15, ty = t >> 4;
#pragma unroll
  for (int r = 0; r < 4; ++r) {
    const int k = ty + r * 16;
    float4 v = *(const float4*)(x + ((size_t)b * CIN + k0 + k) * LHW + l0 + tx * 4);
    Ts[tx*4+0][k] = f2b(v.x);
    Ts[tx*4+1][k] = f2b(v.y);
    Ts[tx*4+2][k] = f2b(v.z);
    Ts[tx*4+3][k] = f2b(v.w);
  }
  __syncthreads();
  const int lr = t >> 2, kc = (t & 3) * 16;
  unsigned short* dst = xt + ((size_t)b * LHW + l0 + lr) * CIN + k0 + kc;
  *(uint4*)dst       = *(const uint4*)&Ts[lr][kc];
  *(uint4*)(dst + 8) = *(const uint4*)&Ts[lr][kc + 8];
}

// ---------------------------------------------------------------------------
// shared MFMA main loop: 128x128 tile, BK=64 + XOR-swizzled LDS (R12-proven)
// ---------------------------------------------------------------------------
template<int RSA, int RSB, int KTOT>
__device__ __forceinline__ void gemm_loop_128(
    const unsigned short* __restrict__ Ab, const unsigned short* __restrict__ Bb,
    unsigned short (&As)[2][4096], unsigned short (&Bs)[2][4096],
    int t, f32x4 acc[4][4]) {
  const int w = t >> 6, lane = t & 63;
  const int wm = w >> 1, wn = w & 1;
  const int arow = t >> 2;
  const int acol = (((t & 3) ^ ((t >> 3) & 3))) * 8;
  const int fr = lane & 15;
  const int g8 = ((lane >> 4) * 8) ^ (((fr >> 1) & 3) * 8);
  for (int k0 = 0; k0 < KTOT; k0 += 64) {
    __syncthreads();
    gload16(Ab + (size_t)arow * RSA + k0 + acol,             &As[0][w * 512]);
    gload16(Ab + (size_t)(64 + arow) * RSA + k0 + acol,      &As[0][2048 + w*512]);
    gload16(Bb + (size_t)arow * RSB + k0 + acol,             &Bs[0][w * 512]);
    gload16(Bb + (size_t)(64 + arow) * RSB + k0 + acol,      &Bs[0][2048 + w*512]);
    gload16(Ab + (size_t)arow * RSA + k0 + 32 + acol,        &As[1][w * 512]);
    gload16(Ab + (size_t)(64 + arow) * RSA + k0 + 32 + acol, &As[1][2048 + w*512]);
    gload16(Bb + (size_t)arow * RSB + k0 + 32 + acol,        &Bs[1][w * 512]);
    gload16(Bb + (size_t)(64 + arow) * RSB + k0 + 32 + acol, &Bs[1][2048 + w*512]);
    __syncthreads();
#pragma unroll
    for (int h = 0; h < 2; ++h) {
      bf16x8 af[4], bf[4];
#pragma unroll
      for (int f = 0; f < 4; ++f) {
        af[f] = *(const bf16x8*)&As[h][(wm*64 + f*16 + fr) * 32 + g8];
        bf[f] = *(const bf16x8*)&Bs[h][(wn*64 + f*16 + fr) * 32 + g8];
      }
#pragma unroll
      for (int i = 0; i < 4; ++i)
#pragma unroll
        for (int j = 0; j < 4; ++j)
          acc[i][j] = __builtin_amdgcn_mfma_f32_16x16x32_bf16(af[i], bf[j], acc[i][j], 0, 0, 0);
    }
  }
}

// ---------------------------------------------------------------------------
// G1: lateral
// ---------------------------------------------------------------------------
__global__ __launch_bounds__(256)
void k_lat_mfma(const unsigned short* __restrict__ xt, const unsigned short* __restrict__ lwb,
                const float* __restrict__ lb, unsigned short* __restrict__ ub) {
  __shared__ __align__(16) unsigned short As[2][4096], Bs[2][4096];
  const int t = threadIdx.x, lane = t & 63, w = t >> 6;
  const int wm = w >> 1, wn = w & 1;
  const int b = blockIdx.z, m0 = blockIdx.y * 128, n0 = blockIdx.x * 128;
  f32x4 acc[4][4] = {};
  gemm_loop_128<512, 512, 512>(xt + ((size_t)b * LHW + m0) * 512,
                               lwb + (size_t)n0 * 512, As, Bs, t, acc);
  const int fr = lane & 15, q4 = (lane >> 4) * 4;
#pragma unroll
  for (int i = 0; i < 4; ++i) {
    const int l = m0 + wm*64 + i*16 + q4;
#pragma unroll
    for (int j = 0; j < 4; ++j) {
      const int o = n0 + wn*64 + j*16 + fr;
      const float bias = lb[o];
      unsigned short* dst = ub + ((size_t)b * LHW + l) * COUT + o;
#pragma unroll
      for (int q = 0; q < 4; ++q)
        dst[(size_t)q * COUT] = f2b(acc[i][j][q] + bias);
    }
  }
}

// ---------------------------------------------------------------------------
// G2: inproj
// ---------------------------------------------------------------------------
__global__ __launch_bounds__(256)
void k_inproj_mfma(const unsigned short* __restrict__ ub, const unsigned short* __restrict__ ipwb,
                   unsigned short* __restrict__ xm_b, unsigned short* __restrict__ zsb) {
  __shared__ __align__(16) unsigned short As[2][4096], Bs[2][4096];
  const int t = threadIdx.x, lane = t & 63, w = t >> 6;
  const int wm = w >> 1, wn = w & 1;
  const int b = blockIdx.z, m0 = blockIdx.y * 128, n0 = blockIdx.x * 128;
  f32x4 acc[4][4] = {};
  gemm_loop_128<256, 256, 256>(ub + ((size_t)b * LHW + m0) * 256,
                               ipwb + (size_t)n0 * 256, As, Bs, t, acc);
  const int fr = lane & 15, q4 = (lane >> 4) * 4;
  const bool isz = (n0 >= 512);
#pragma unroll
  for (int i = 0; i < 4; ++i) {
    const int l = m0 + wm*64 + i*16 + q4;
#pragma unroll
    for (int j = 0; j < 4; ++j) {
      const int e = n0 + wn*64 + j*16 + fr;
      if (isz) {
        unsigned short* dst = zsb + ((size_t)b * LHW + l) * DIN + (e - 512);
#pragma unroll
        for (int q = 0; q < 4; ++q)
          dst[(size_t)q * DIN] = f2b(siluf(acc[i][j][q]));
      } else {
        unsigned short* dst = xm_b + ((size_t)b * LHW + l) * DIN + e;
#pragma unroll
        for (int q = 0; q < 4; ++q)
          dst[(size_t)q * DIN] = f2b(acc[i][j][q]);
      }
    }
  }
}

// ---------------------------------------------------------------------------
// K3: depthwise causal conv1d, 8 rows/thread
// ---------------------------------------------------------------------------
__global__ __launch_bounds__(256)
void k_conv1d(const unsigned short* __restrict__ xm_b, const float* __restrict__ cw,
              const float* __restrict__ cb, unsigned short* __restrict__ xc_b) {
  const int tid = blockIdx.x * 256 + threadIdx.x;
  const int e8 = tid & 63;
  const int lg = tid >> 6;
  const int l0 = (lg & 511) * 8;
  const int b  = lg >> 9;
  const int e0 = e8 * 8;
  float bias[8];
  *(float4*)&bias[0] = *(const float4*)(cb + e0);
  *(float4*)&bias[4] = *(const float4*)(cb + e0 + 4);
  float wv[8][4];
#pragma unroll
  for (int q = 0; q < 8; ++q) {
    float4 w4 = *(const float4*)(cw + (e0 + q) * 4);
    wv[q][0] = w4.x; wv[q][1] = w4.y; wv[q][2] = w4.z; wv[q][3] = w4.w;
  }
  const unsigned short* base = xm_b + ((size_t)b * LHW + l0) * DIN + e0;
  uint4 rows[11];
  const uint4 z4 = make_uint4(0u, 0u, 0u, 0u);
#pragma unroll
  for (int r = 0; r < 11; ++r) {
    const int ll = r - 3;
    rows[r] = (l0 + ll >= 0) ? *(const uint4*)(base + (ptrdiff_t)ll * DIN) : z4;
  }
  unsigned short* outb = xc_b + ((size_t)b * LHW + l0) * DIN + e0;
#pragma unroll
  for (int j = 0; j < 8; ++j) {
    float acc[8];
#pragma unroll
    for (int q = 0; q < 8; ++q) acc[q] = bias[q];
#pragma unroll
    for (int k = 0; k < 4; ++k) {
      const uint4 raw = rows[j + k];
      acc[0] = fmaf(b2f(raw.x),       wv[0][k], acc[0]);
      acc[1] = fmaf(b2f(raw.x >> 16), wv[1][k], acc[1]);
      acc[2] = fmaf(b2f(raw.y),       wv[2][k], acc[2]);
      acc[3] = fmaf(b2f(raw.y >> 16), wv[3][k], acc[3]);
      acc[4] = fmaf(b2f(raw.z),       wv[4][k], acc[4]);
      acc[5] = fmaf(b2f(raw.z >> 16), wv[5][k], acc[5]);
      acc[6] = fmaf(b2f(raw.w),       wv[6][k], acc[6]);
      acc[7] = fmaf(b2f(raw.w >> 16), wv[7][k], acc[7]);
    }
    uint4 o;
    o.x = (unsigned)f2b(siluf(acc[0])) | ((unsigned)f2b(siluf(acc[1])) << 16);
    o.y = (unsigned)f2b(siluf(acc[2])) | ((unsigned)f2b(siluf(acc[3])) << 16);
    o.z = (unsigned)f2b(siluf(acc[4])) | ((unsigned)f2b(siluf(acc[5])) << 16);
    o.w = (unsigned)f2b(siluf(acc[6])) | ((unsigned)f2b(siluf(acc[7])) << 16);
    *(uint4*)(outb + (size_t)j * DIN) = o;
  }
}

// ---------------------------------------------------------------------------
// G3: fused xproj+dt GEMM
// ---------------------------------------------------------------------------
__global__ __launch_bounds__(256)
void k_xdt_mfma(const unsigned short* __restrict__ xc_b, const unsigned short* __restrict__ wfb,
                const float* __restrict__ dtpb,
                unsigned short* __restrict__ dtb, float* __restrict__ proj) {
  __shared__ __align__(16) unsigned short As[2][4096], Bs[2][4096];
  const int t = threadIdx.x, lane = t & 63, w = t >> 6;
  const int wm = w >> 1, wn = w & 1;
  const int b = blockIdx.z, m0 = blockIdx.x * 128, n0 = blockIdx.y * 128;
  f32x4 acc[4][4] = {};
  gemm_loop_128<512, 512, 512>(xc_b + ((size_t)b * LHW + m0) * 512,
                               wfb + (size_t)n0 * 512, As, Bs, t, acc);
  const int fr = lane & 15, q4 = (lane >> 4) * 4;
#pragma unroll
  for (int i = 0; i < 4; ++i) {
    const int l = m0 + wm*64 + i*16 + q4;
#pragma unroll
    for (int j = 0; j < 4; ++j) {
      const int c = n0 + wn*64 + j*16 + fr;
      if (c < 512) {
        const float bias = dtpb[c];
        unsigned short* dst = dtb + ((size_t)b * LHW + l) * 512 + c;
#pragma unroll
        for (int q = 0; q < 4; ++q)
          dst[(size_t)q * 512] = f2b(splusf(acc[i][j][q] + bias));
      } else if (c < 560) {
        float* dst = proj + ((size_t)b * LHW + l) * 48 + (c - 512);
#pragma unroll
        for (int q = 0; q < 4; ++q)
          dst[(size_t)q * 48] = acc[i][j][q];
      }
    }
  }
}

// ---------------------------------------------------------------------------
// K5: scan phase A — 1 thread per d, 16 states, packed-f32 math, CHL=16.
// Outputs: Sst bf16 (local end states), SDT f32 (sum dt per chunk-d)
// ---------------------------------------------------------------------------
__global__ __launch_bounds__(512, 4)
void k_scanA(const float* __restrict__ proj, const unsigned short* __restrict__ dtb,
             const unsigned short* __restrict__ xc_b, const float* __restrict__ A_log,
             unsigned short* __restrict__ Sst, float* __restrict__ SDT) {
  __shared__ float prs[CHL * 16];
  const int bx = blockIdx.x;                 // chunkid
  const int b = bx >> 8, c = bx & 255;
  const int d = threadIdx.x;
  const size_t rbase = (size_t)b * LHW + c * CHL;
  for (int i = d; i < CHL * 4; i += 512) {
    const int row = i >> 2, c4 = i & 3;
    *(float4*)&prs[row * 16 + c4 * 4] = *(const float4*)(proj + (rbase + row) * 48 + 16 + c4 * 4);
  }
  float An[16];
#pragma unroll
  for (int q = 0; q < 4; ++q) {
    float4 a4 = *(const float4*)(A_log + d*16 + q*4);
    An[q*4+0] = -__expf(a4.x); An[q*4+1] = -__expf(a4.y);
    An[q*4+2] = -__expf(a4.z); An[q*4+3] = -__expf(a4.w);
  }
  f32x2 h2[8];
#pragma unroll
  for (int k = 0; k < 8; ++k) h2[k] = (f32x2){0.f, 0.f};
  const float An0 = An[0];
  bool lin = true;
#pragma unroll
  for (int n = 1; n < 16; ++n)
    lin = lin && (fabsf(An[n] - (n + 1) * An0) <= 1e-4f * fabsf(An[n]));
  float sdt = 0.f;
  const unsigned short* dt0 = dtb + rbase * 512 + d;
  const unsigned short* xc0 = xc_b + rbase * DIN + d;
  __syncthreads();
  for (int i = 0; i < CHL; ++i) {
    const float dt = b2f(dt0[(size_t)i * 512]);
    sdt += dt;
    const float dtx = dt * b2f(xc0[(size_t)i * DIN]);
    const f32x2 dtx2 = (f32x2){dtx, dtx};
    f32x2 dA2[8];
    if (lin) {
      const float e1 = __expf(dt * An0);
      const float e2 = e1*e1, e3 = e2*e1, e4 = e2*e2, e8 = e4*e4;
      const f32x2 e4v = (f32x2){e4, e4}, e8v = (f32x2){e8, e8};
      dA2[0] = (f32x2){e1, e2};
      dA2[1] = (f32x2){e3, e4};
      dA2[2] = pk_mul(dA2[0], e4v);
      dA2[3] = pk_mul(dA2[1], e4v);
      dA2[4] = pk_mul(dA2[0], e8v);
      dA2[5] = pk_mul(dA2[1], e8v);
      dA2[6] = pk_mul(dA2[2], e8v);
      dA2[7] = pk_mul(dA2[3], e8v);
    } else {
#pragma unroll
      for (int k = 0; k < 8; ++k)
        dA2[k] = (f32x2){__expf(dt * An[2*k]), __expf(dt * An[2*k+1])};
    }
    const f32x2* B2 = (const f32x2*)&prs[i * 16];
#pragma unroll
    for (int k = 0; k < 8; ++k)
      h2[k] = pk_fma(dA2[k], h2[k], pk_mul(dtx2, B2[k]));
  }
  unsigned short* o = Sst + ((size_t)bx * 512 + d) * 16;
  uint4 p0, p1;
  p0.x = (unsigned)f2b(h2[0].x) | ((unsigned)f2b(h2[0].y) << 16);
  p0.y = (unsigned)f2b(h2[1].x) | ((unsigned)f2b(h2[1].y) << 16);
  p0.z = (unsigned)f2b(h2[2].x) | ((unsigned)f2b(h2[2].y) << 16);
  p0.w = (unsigned)f2b(h2[3].x) | ((unsigned)f2b(h2[3].y) << 16);
  p1.x = (unsigned)f2b(h2[4].x) | ((unsigned)f2b(h2[4].y) << 16);
  p1.y = (unsigned)f2b(h2[5].x) | ((unsigned)f2b(h2[5].y) << 16);
  p1.z = (unsigned)f2b(h2[6].x) | ((unsigned)f2b(h2[6].y) << 16);
  p1.w = (unsigned)f2b(h2[7].x) | ((unsigned)f2b(h2[7].y) << 16);
  *(uint4*)o       = p0;
  *(uint4*)(o + 8) = p1;
  SDT[(size_t)bx * 512 + d] = sdt;
}

// ---------------------------------------------------------------------------
// K6: scan phase B — combine chunk summaries (P from SDT); Sst/hst bf16
// ---------------------------------------------------------------------------
__global__ __launch_bounds__(256)
void k_scanB(const unsigned short* __restrict__ Sst, const float* __restrict__ SDT,
             const float* __restrict__ A_log, unsigned short* __restrict__ hst) {
  const int tid = blockIdx.x * 256 + threadIdx.x;
  const int n = tid & 15;
  const int d = (tid >> 4) & 511;
  const int b = tid >> 13;
  const float An = -__expf(A_log[d * 16 + n]);
  float h = 0.f;
  for (int c = 0; c < NCHK; ++c) {
    const size_t idx = (size_t)((b*NCHK + c)*512 + d);
    hst[idx*16 + n] = f2b(h);
    h = __expf(SDT[idx] * An) * h + b2f(Sst[idx*16 + n]);
  }
}

// ---------------------------------------------------------------------------
// K7: scan phase C — 1 thread per d, 16 states, packed-f32 math, CHL=16
// ---------------------------------------------------------------------------
__global__ __launch_bounds__(512, 4)
void k_scanC(const float* __restrict__ proj, const unsigned short* __restrict__ dtb,
             const unsigned short* __restrict__ xc_b,
             const unsigned short* __restrict__ zsb, const unsigned short* __restrict__ hst,
             const float* __restrict__ A_log, const float* __restrict__ Dpar,
             unsigned short* __restrict__ ydata) {
  __shared__ float prs[CHL * 32];
  const int bx = blockIdx.x;                 // chunkid
  const int b = bx >> 8, c = bx & 255;
  const int d = threadIdx.x;
  const size_t rbase = (size_t)b * LHW + c * CHL;
  for (int i = d; i < CHL * 8; i += 512) {
    const int row = i >> 3, c4 = i & 7;
    *(float4*)&prs[row * 32 + c4 * 4] = *(const float4*)(proj + (rbase + row) * 48 + 16 + c4 * 4);
  }
  float An[16];
#pragma unroll
  for (int q = 0; q < 4; ++q) {
    float4 a4 = *(const float4*)(A_log + d*16 + q*4);
    An[q*4+0] = -__expf(a4.x); An[q*4+1] = -__expf(a4.y);
    An[q*4+2] = -__expf(a4.z); An[q*4+3] = -__expf(a4.w);
  }
  f32x2 h2[8];
  {
    const unsigned short* hsrc = hst + ((size_t)bx * 512 + d) * 16;
    uint4 p0 = *(const uint4*)hsrc;
    uint4 p1 = *(const uint4*)(hsrc + 8);
    h2[0] = (f32x2){b2f(p0.x), b2f(p0.x >> 16)};
    h2[1] = (f32x2){b2f(p0.y), b2f(p0.y >> 16)};
    h2[2] = (f32x2){b2f(p0.z), b2f(p0.z >> 16)};
    h2[3] = (f32x2){b2f(p0.w), b2f(p0.w >> 16)};
    h2[4] = (f32x2){b2f(p1.x), b2f(p1.x >> 16)};
    h2[5] = (f32x2){b2f(p1.y), b2f(p1.y >> 16)};
    h2[6] = (f32x2){b2f(p1.z), b2f(p1.z >> 16)};
    h2[7] = (f32x2){b2f(p1.w), b2f(p1.w >> 16)};
  }
  const float An0 = An[0];
  bool lin = true;
#pragma unroll
  for (int n = 1; n < 16; ++n)
    lin = lin && (fabsf(An[n] - (n + 1) * An0) <= 1e-4f * fabsf(An[n]));
  const float dp = Dpar[d];
  const unsigned short* dt0 = dtb + rbase * 512 + d;
  const unsigned short* xc0 = xc_b + rbase * DIN + d;
  const unsigned short* zs0 = zsb + rbase * DIN + d;
  unsigned short* y0 = ydata + rbase * DIN + d;
  __syncthreads();
  for (int i = 0; i < CHL; ++i) {
    const float dt = b2f(dt0[(size_t)i * 512]);
    const float xt = b2f(xc0[(size_t)i * DIN]);
    const float zv = b2f(zs0[(size_t)i * DIN]);
    const float dtx = dt * xt;
    const f32x2 dtx2 = (f32x2){dtx, dtx};
    f32x2 dA2[8];
    if (lin) {
      const float e1 = __expf(dt * An0);
      const float e2 = e1*e1, e3 = e2*e1, e4 = e2*e2, e8 = e4*e4;
      const f32x2 e4v = (f32x2){e4, e4}, e8v = (f32x2){e8, e8};
      dA2[0] = (f32x2){e1, e2};
      dA2[1] = (f32x2){e3, e4};
      dA2[2] = pk_mul(dA2[0], e4v);
      dA2[3] = pk_mul(dA2[1], e4v);
      dA2[4] = pk_mul(dA2[0], e8v);
      dA2[5] = pk_mul(dA2[1], e8v);
      dA2[6] = pk_mul(dA2[2], e8v);
      dA2[7] = pk_mul(dA2[3], e8v);
    } else {
#pragma unroll
      for (int k = 0; k < 8; ++k)
        dA2[k] = (f32x2){__expf(dt * An[2*k]), __expf(dt * An[2*k+1])};
    }
    const f32x2* B2 = (const f32x2*)&prs[i * 32];
    const f32x2* C2 = (const f32x2*)&prs[i * 32 + 16];
    f32x2 ya = (f32x2){0.f, 0.f}, yb = (f32x2){0.f, 0.f};
#pragma unroll
    for (int k = 0; k < 8; ++k) {
      h2[k] = pk_fma(dA2[k], h2[k], pk_mul(dtx2, B2[k]));
      if (k & 1) yb = pk_fma(h2[k], C2[k], yb);
      else       ya = pk_fma(h2[k], C2[k], ya);
    }
    const float y = (ya.x + ya.y) + (yb.x + yb.y);
    const float ov = (y + xt * dp) * zv;
    y0[(size_t)i * DIN] = f2b(ov);
  }
}

// ---------------------------------------------------------------------------
// G4: outproj + residual(ub) -> padded channel-last bf16 xrp
// ---------------------------------------------------------------------------
__global__ __launch_bounds__(256)
void k_outproj_mfma(const unsigned short* __restrict__ ydata, const unsigned short* __restrict__ opwb,
                    const unsigned short* __restrict__ ub, unsigned short* __restrict__ xrp) {
  __shared__ __align__(16) unsigned short As[2][4096], Bs[2][4096];
  const int t = threadIdx.x, lane = t & 63, w = t >> 6;
  const int wm = w >> 1, wn = w & 1;
  const int b = blockIdx.z, m0 = blockIdx.y * 128, n0 = blockIdx.x * 128;
  f32x4 acc[4][4] = {};
  gemm_loop_128<512, 512, 512>(ydata + ((size_t)b * LHW + m0) * 512,
                               opwb + (size_t)n0 * 512, As, Bs, t, acc);
  const int fr = lane & 15, q4 = (lane >> 4) * 4;
#pragma unroll
  for (int i = 0; i < 4; ++i) {
    const int lbase = m0 + wm*64 + i*16 + q4;
#pragma unroll
    for (int q = 0; q < 4; ++q) {
      const int l = lbase + q;
      const int pos = ((l >> 6) + 1) * PW + (l & 63) + 1;
#pragma unroll
      for (int j = 0; j < 4; ++j) {
        const int o = n0 + wn*64 + j*16 + fr;
        const float r = b2f(ub[((size_t)b * LHW + l) * COUT + o]);
        xrp[((size_t)b * PPOS + pos) * COUT + o] = f2b(acc[i][j][q] + r);
      }
    }
  }
}

// ---------------------------------------------------------------------------
// G5: refine 3x3 conv, 128x128 tile, BK=128 (4 sub-slices/barrier), swizzled
// ---------------------------------------------------------------------------
__global__ __launch_bounds__(256)
void k_refine_mfma(const unsigned short* __restrict__ Aw,
                   const unsigned short* __restrict__ xrp,
                   const float* __restrict__ rb, const float* __restrict__ bng,
                   const float* __restrict__ bnb, const float* __restrict__ bnm,
                   const float* __restrict__ bnv, float* __restrict__ out) {
  __shared__ __align__(16) unsigned short As[4][4096], Bs[4][4096];
  const int t = threadIdx.x;
  const int lane = t & 63;
  const int w = t >> 6;
  const int wm = w >> 1, wn = w & 1;
  const int b  = blockIdx.z;
  const int m0 = blockIdx.y * 128;
  const int n0 = blockIdx.x * 128;
  const int y0 = n0 >> 6;
  const unsigned short* xb = xrp + (size_t)b * PPOS * COUT;
  const int arow = t >> 2;
  const int acol = (((t & 3) ^ ((t >> 3) & 3))) * 8;
  const int fr = lane & 15;
  const int g8 = ((lane >> 4) * 8) ^ (((fr >> 1) & 3) * 8);

#define RF_STAGE(ks, buf) {                                                            \
    const int tap_ = (ks) >> 3;                                                        \
    const int i0_  = ((ks) & 7) * 32;                                                  \
    const int ky_  = tap_ / 3, kx_ = tap_ - ky_ * 3;                                   \
    const int k0_  = tap_ * 256 + i0_;                                                 \
    const unsigned short* ga_ = Aw + (size_t)(m0 + arow) * 2304 + k0_ + acol;          \
    const unsigned short* gb_ = xb + ((size_t)((y0 + ky_) * PW + kx_ + arow)) * COUT + i0_ + acol; \
    gload16(ga_,              &As[buf][w * 512]);                                      \
    gload16(ga_ + 64 * 2304,  &As[buf][2048 + w * 512]);                               \
    gload16(gb_,              &Bs[buf][w * 512]);                                      \
    gload16(gb_ + PW * COUT,  &Bs[buf][2048 + w * 512]);                               \
  }

  f32x4 acc[4][4] = {};
  for (int ks = 0; ks < 72; ks += 4) {
    __syncthreads();
    RF_STAGE(ks, 0);
    RF_STAGE(ks + 1, 1);
    RF_STAGE(ks + 2, 2);
    RF_STAGE(ks + 3, 3);
    __syncthreads();
#pragma unroll
    for (int h = 0; h < 4; ++h) {
      bf16x8 af[4], bfr[4];
#pragma unroll
      for (int f = 0; f < 4; ++f) {
        af[f]  = *(const bf16x8*)&As[h][(wm*64 + f*16 + fr) * 32 + g8];
        bfr[f] = *(const bf16x8*)&Bs[h][(wn*64 + f*16 + fr) * 32 + g8];
      }
#pragma unroll
      for (int i = 0; i < 4; ++i)
#pragma unroll
        for (int j = 0; j < 4; ++j)
          acc[i][j] = __builtin_amdgcn_mfma_f32_16x16x32_bf16(af[i], bfr[j], acc[i][j], 0, 0, 0);
    }
  }
#undef RF_STAGE
  const int q4 = (lane >> 4) * 4;
#pragma unroll
  for (int i = 0; i < 4; ++i) {
    const int obase = m0 + wm*64 + i*16 + q4;
#pragma unroll
    for (int q = 0; q < 4; ++q) {
      const int o = obase + q;
      const float inv = bng[o] * rsqrtf(bnv[o] + 1e-5f);
      const float sh  = (rb[o] - bnm[o]) * inv + bnb[o];
      float* orow = out + ((size_t)b * COUT + o) * LHW + n0 + wn*64 + fr;
#pragma unroll
      for (int j = 0; j < 4; ++j)
        orow[j*16] = fmaxf(fmaf(acc[i][j][q], inv, sh), 0.f);
    }
  }
}

// ---------------------------------------------------------------------------
extern "C" void kernel_launch(void* const* d_in, const int* in_sizes, int n_in,
                              void* d_out, int out_size, void* d_ws, size_t ws_size,
                              hipStream_t stream) {
  const float* x    = (const float*)d_in[0];
  const float* lw   = (const float*)d_in[1];
  const float* lb   = (const float*)d_in[2];
  const float* ipw  = (const float*)d_in[3];
  const float* cw   = (const float*)d_in[4];
  const float* cb   = (const float*)d_in[5];
  const float* xpw  = (const float*)d_in[6];
  const float* dtpw = (const float*)d_in[7];
  const float* dtpb = (const float*)d_in[8];
  const float* Alog = (const float*)d_in[9];
  const float* Dpar = (const float*)d_in[10];
  const float* opw  = (const float*)d_in[11];
  const float* rw   = (const float*)d_in[12];
  const float* rb   = (const float*)d_in[13];
  const float* bng  = (const float*)d_in[14];
  const float* bnb  = (const float*)d_in[15];
  const float* bnm  = (const float*)d_in[16];
  const float* bnv  = (const float*)d_in[17];
  float* out = (float*)d_out;

  float* ws = (float*)d_ws;
  unsigned short* ub   = (unsigned short*)ws;                      // 8.4M us
  unsigned short* xt   = (unsigned short*)(ws + 4194304);          // 16.8M us (reused: dtb, xrp)
  unsigned short* xm_b = (unsigned short*)(ws + 12582912);         // 16.8M us (reused as ydata)
  unsigned short* xc_b = (unsigned short*)(ws + 20971520);         // 16.8M us
  unsigned short* zsb  = (unsigned short*)(ws + 29360128);         // 16.8M us
  float* proj = ws + 37748736;                                     //  1.57M f
  unsigned short* Sst = (unsigned short*)(ws + 39321600);          // 16.8M us (NB*NCHK*512*16)
  float* SDT  = ws + 47710208;                                     //  1.05M f (NB*NCHK*512)
  unsigned short* hst = (unsigned short*)(ws + 48758784);          // 16.8M us
  unsigned short* wb  = (unsigned short*)(ws + 64487424);          //  1.15M us
  unsigned short* wfb = (unsigned short*)(ws + 65060864);          //  0.33M us
  unsigned short* lwb  = wb;
  unsigned short* ipwb = wb + WO1;
  unsigned short* opwb = wb + WO3;
  unsigned short* Aw   = wb + WO4;
  unsigned short* ydata = xm_b;
  unsigned short* dtb   = xt;
  unsigned short* xrp   = xt;

  k_wprep<<<dim3(5760), 256, 0, stream>>>(lw, ipw, xpw, opw, rw, dtpw, wb, wfb);
  k_xpose<<<dim3(64, 8, 8), 256, 0, stream>>>(x, xt);
  k_lat_mfma<<<dim3(2, 32, 8), 256, 0, stream>>>(xt, lwb, lb, ub);
  k_inproj_mfma<<<dim3(8, 32, 8), 256, 0, stream>>>(ub, ipwb, xm_b, zsb);
  k_conv1d<<<dim3(1024), 256, 0, stream>>>(xm_b, cw, cb, xc_b);
  k_xdt_mfma<<<dim3(32, 5, 8), 256, 0, stream>>>(xc_b, wfb, dtpb, dtb, proj);
  k_scanA<<<dim3(NB * NCHK), 512, 0, stream>>>(proj, dtb, xc_b, Alog, Sst, SDT);
  k_scanB<<<dim3(256), 256, 0, stream>>>(Sst, SDT, Alog, hst);
  k_scanC<<<dim3(NB * NCHK), 512, 0, stream>>>(proj, dtb, xc_b, zsb, hst, Alog, Dpar, ydata);
  hipMemsetAsync(xrp, 0, (size_t)NB * PPOS * COUT * sizeof(unsigned short), stream);
  k_outproj_mfma<<<dim3(2, 32, 8), 256, 0, stream>>>(ydata, opwb, ub, xrp);
  k_refine_mfma<<<dim3(32, 2, 8), 256, 0, stream>>>(Aw, xrp, rb, bng, bnb, bnm, bnv, out);
}